// Round 1
// baseline (686.835 us; speedup 1.0000x reference)
//
#include <hip/hip_runtime.h>
#include <math.h>

#define NEG_SLOPE 0.2f

// ---------------------------------------------------------------------------
// Kernel 1: per-edge histogram: deg[dst]++, ea_sum[dst] += edge_attr[e]
// ---------------------------------------------------------------------------
__global__ void edge_hist(const int* __restrict__ ei, const float* __restrict__ ea,
                          int* __restrict__ deg, float* __restrict__ ea_sum, int E) {
    int e = blockIdx.x * blockDim.x + threadIdx.x;
    if (e < E) {
        int d = ei[E + e];           // dst row of edge_index [2,E]
        atomicAdd(&deg[d], 1);
        atomicAdd(&ea_sum[d], ea[e]);
    }
}

// ---------------------------------------------------------------------------
// Kernel 2: single-block exclusive scan of deg -> row_ptr (and wptr copy),
// plus ea_loop = ea_sum / max(deg,1).  n = 20000, one block of 1024 threads.
// ---------------------------------------------------------------------------
__global__ void scan_deg(const int* __restrict__ deg, const float* __restrict__ ea_sum,
                         int* __restrict__ row_ptr, int* __restrict__ wptr,
                         float* __restrict__ ea_loop, int n) {
    __shared__ int sd[1024];
    __shared__ int carry_s;
    int tid = threadIdx.x;
    if (tid == 0) carry_s = 0;
    __syncthreads();
    for (int base = 0; base < n; base += 1024) {
        int i = base + tid;
        int v = (i < n) ? deg[i] : 0;
        sd[tid] = v;
        __syncthreads();
        // Hillis-Steele inclusive scan
        for (int off = 1; off < 1024; off <<= 1) {
            int add = (tid >= off) ? sd[tid - off] : 0;
            __syncthreads();
            sd[tid] += add;
            __syncthreads();
        }
        int incl = sd[tid];
        int carry = carry_s;
        if (i < n) {
            int excl = carry + incl - v;
            row_ptr[i] = excl;
            wptr[i]    = excl;
            ea_loop[i] = ea_sum[i] / fmaxf((float)v, 1.0f);
        }
        __syncthreads();
        if (tid == 1023) carry_s = carry + sd[1023];
        __syncthreads();
    }
    if (tid == 0) row_ptr[n] = carry_s;
}

// ---------------------------------------------------------------------------
// Kernel 3: scatter edges into CSR order (bucket order nondeterministic; sums
// are order-insensitive up to fp rounding which is << threshold).
// ---------------------------------------------------------------------------
__global__ void edge_scatter(const int* __restrict__ ei, const float* __restrict__ ea,
                             int* __restrict__ wptr, int* __restrict__ ssrc,
                             float* __restrict__ sea, int E) {
    int e = blockIdx.x * blockDim.x + threadIdx.x;
    if (e < E) {
        int d = ei[E + e];
        int pos = atomicAdd(&wptr[d], 1);
        ssrc[pos] = ei[e];
        sea[pos]  = ea[e];
    }
}

// ---------------------------------------------------------------------------
// Kernel 4: fp32 GEMM + bias: C[M,N] = A[M,K] @ B[K,N] + bias[N]
// 64x64 tile, BK=16, 256 threads, 4x4 microtile.
// ---------------------------------------------------------------------------
__global__ void gemm_bias(const float* __restrict__ A, const float* __restrict__ B,
                          const float* __restrict__ bias, float* __restrict__ C,
                          int M, int N, int K) {
    __shared__ float As[16][68];   // [k][m], padded
    __shared__ float Bs[16][68];   // [k][n], padded
    int tid = threadIdx.x;
    int tx = tid & 15, ty = tid >> 4;
    int m0 = blockIdx.x * 64, n0 = blockIdx.y * 64;
    float acc[4][4] = {};
    for (int kk = 0; kk < K; kk += 16) {
        for (int t = tid; t < 1024; t += 256) {
            int m = t >> 4, k = t & 15;
            int gm = m0 + m;
            As[k][m] = (gm < M) ? A[(size_t)gm * K + kk + k] : 0.0f;
        }
        for (int t = tid; t < 1024; t += 256) {
            int k = t >> 6, n = t & 63;
            Bs[k][n] = B[(size_t)(kk + k) * N + n0 + n];
        }
        __syncthreads();
#pragma unroll
        for (int k = 0; k < 16; ++k) {
            float a[4], b[4];
#pragma unroll
            for (int i = 0; i < 4; ++i) a[i] = As[k][ty * 4 + i];
#pragma unroll
            for (int j = 0; j < 4; ++j) b[j] = Bs[k][tx * 4 + j];
#pragma unroll
            for (int i = 0; i < 4; ++i)
#pragma unroll
                for (int j = 0; j < 4; ++j) acc[i][j] += a[i] * b[j];
        }
        __syncthreads();
    }
#pragma unroll
    for (int i = 0; i < 4; ++i) {
        int gm = m0 + ty * 4 + i;
        if (gm < M) {
#pragma unroll
            for (int j = 0; j < 4; ++j) {
                int gn = n0 + tx * 4 + j;
                C[(size_t)gm * N + gn] = acc[i][j] + bias[gn];
            }
        }
    }
}

// ---------------------------------------------------------------------------
// Kernel 5: fused GATv2 gather + score + online-softmax + aggregate + relu.
// One wave (64 lanes) per destination node; 4 nodes per 256-thread block.
// Lane owns NV = HC/64 contiguous channels (never crossing a head boundary),
// so online-softmax state (m,l) is per-lane scalar.
// HC=256,C=32 (layer1: NV=4, reduce width 8) | HC=128,C=128 (layer2: NV=2, w64)
// ---------------------------------------------------------------------------
template <int HC, int C>
__global__ void gat_agg(const float* __restrict__ xl, const float* __restrict__ xr,
                        const float* __restrict__ We, const float* __restrict__ att,
                        const float* __restrict__ bias,
                        const int* __restrict__ row_ptr, const int* __restrict__ ssrc,
                        const float* __restrict__ sea, const float* __restrict__ ea_loop,
                        float* __restrict__ out, int n) {
    constexpr int NV = HC / 64;      // channels per lane
    constexpr int G  = C / NV;       // reduction group width (lanes per head)
    int wave = threadIdx.x >> 6;
    int lane = threadIdx.x & 63;
    int node = blockIdx.x * 4 + wave;
    if (node >= n) return;

    float xr_r[NV], We_r[NV], att_r[NV], o[NV];
    {
        const float* p;
        p = xr + (size_t)node * HC + lane * NV;
        if constexpr (NV == 4) { float4 t = *(const float4*)p; xr_r[0]=t.x; xr_r[1]=t.y; xr_r[2]=t.z; xr_r[3]=t.w; }
        else                   { float2 t = *(const float2*)p; xr_r[0]=t.x; xr_r[1]=t.y; }
        p = We + lane * NV;
        if constexpr (NV == 4) { float4 t = *(const float4*)p; We_r[0]=t.x; We_r[1]=t.y; We_r[2]=t.z; We_r[3]=t.w; }
        else                   { float2 t = *(const float2*)p; We_r[0]=t.x; We_r[1]=t.y; }
        p = att + lane * NV;
        if constexpr (NV == 4) { float4 t = *(const float4*)p; att_r[0]=t.x; att_r[1]=t.y; att_r[2]=t.z; att_r[3]=t.w; }
        else                   { float2 t = *(const float2*)p; att_r[0]=t.x; att_r[1]=t.y; }
    }
#pragma unroll
    for (int j = 0; j < NV; ++j) o[j] = 0.0f;
    float m = -3.402823e38f, l = 0.0f;

    int start = row_ptr[node], end = row_ptr[node + 1];
    float ea_l = ea_loop[node];

    for (int e = start; e <= end; ++e) {
        int src; float w;
        if (e < end) { src = ssrc[e]; w = sea[e]; }
        else         { src = node;    w = ea_l;   }

        float xls[NV];
        const float* p = xl + (size_t)src * HC + lane * NV;
        if constexpr (NV == 4) { float4 t = *(const float4*)p; xls[0]=t.x; xls[1]=t.y; xls[2]=t.z; xls[3]=t.w; }
        else                   { float2 t = *(const float2*)p; xls[0]=t.x; xls[1]=t.y; }

        float vs = 0.0f;
#pragma unroll
        for (int j = 0; j < NV; ++j) {
            float mm = xls[j] + xr_r[j] + w * We_r[j];
            float lr = (mm > 0.0f) ? mm : NEG_SLOPE * mm;
            vs += lr * att_r[j];
        }
#pragma unroll
        for (int off = G / 2; off > 0; off >>= 1) vs += __shfl_xor(vs, off, G);
        // vs == score s for this lane's head; online softmax update
        float mn = fmaxf(m, vs);
        float scale = __expf(m - mn);
        float pr    = __expf(vs - mn);
#pragma unroll
        for (int j = 0; j < NV; ++j) o[j] = o[j] * scale + pr * xls[j];
        l = l * scale + pr;
        m = mn;
    }

    float inv = 1.0f / (l + 1e-16f);
    const float* bp = bias + lane * NV;
    float b_r[NV];
    if constexpr (NV == 4) { float4 t = *(const float4*)bp; b_r[0]=t.x; b_r[1]=t.y; b_r[2]=t.z; b_r[3]=t.w; }
    else                   { float2 t = *(const float2*)bp; b_r[0]=t.x; b_r[1]=t.y; }
    float* op = out + (size_t)node * HC + lane * NV;
    if constexpr (NV == 4) {
        float4 t;
        t.x = fmaxf(o[0] * inv + b_r[0], 0.0f);
        t.y = fmaxf(o[1] * inv + b_r[1], 0.0f);
        t.z = fmaxf(o[2] * inv + b_r[2], 0.0f);
        t.w = fmaxf(o[3] * inv + b_r[3], 0.0f);
        *(float4*)op = t;
    } else {
        float2 t;
        t.x = fmaxf(o[0] * inv + b_r[0], 0.0f);
        t.y = fmaxf(o[1] * inv + b_r[1], 0.0f);
        *(float2*)op = t;
    }
}

// ---------------------------------------------------------------------------
// Kernel 6: column partial sums of h2 [n,128] -> partial[gridDim.x*128]
// ---------------------------------------------------------------------------
__global__ void pool_partial(const float* __restrict__ h2, float* __restrict__ partial, int n) {
    int t = threadIdx.x;          // 0..127
    float s = 0.0f;
    for (int r = blockIdx.x; r < n; r += gridDim.x) s += h2[(size_t)r * 128 + t];
    partial[blockIdx.x * 128 + t] = s;
}

// ---------------------------------------------------------------------------
// Kernel 7: finish pooling, softmax over 128, sigmoid(alpha). 1 block x 128.
// ---------------------------------------------------------------------------
__global__ void pool_final(const float* __restrict__ partial, int nb,
                           const float* __restrict__ alpha_in,
                           float* __restrict__ out, int n) {
    __shared__ float red[4];
    int t = threadIdx.x;          // 0..127
    float s = 0.0f;
    for (int b = 0; b < nb; ++b) s += partial[b * 128 + t];
    float mean = s / (float)n;
    // max over 128 (2 waves)
    float mx = mean;
#pragma unroll
    for (int off = 32; off > 0; off >>= 1) mx = fmaxf(mx, __shfl_xor(mx, off, 64));
    if ((t & 63) == 0) red[t >> 6] = mx;
    __syncthreads();
    mx = fmaxf(red[0], red[1]);
    float ex = __expf(mean - mx);
    float sm = ex;
#pragma unroll
    for (int off = 32; off > 0; off >>= 1) sm += __shfl_xor(sm, off, 64);
    if ((t & 63) == 0) red[2 + (t >> 6)] = sm;
    __syncthreads();
    sm = red[2] + red[3];
    out[t] = ex / sm;
    if (t == 0) out[128] = 1.0f / (1.0f + __expf(-alpha_in[0]));
}

// ---------------------------------------------------------------------------
extern "C" void kernel_launch(void* const* d_in, const int* in_sizes, int n_in,
                              void* d_out, int out_size, void* d_ws, size_t ws_size,
                              hipStream_t stream) {
    const float* x    = (const float*)d_in[0];
    const int*   ei   = (const int*)d_in[1];    // [2,E] int32
    const float* ea   = (const float*)d_in[2];
    const float* W1l  = (const float*)d_in[3];
    const float* b1l  = (const float*)d_in[4];
    const float* W1r  = (const float*)d_in[5];
    const float* b1r  = (const float*)d_in[6];
    const float* We1  = (const float*)d_in[7];
    const float* att1 = (const float*)d_in[8];
    const float* bias1= (const float*)d_in[9];
    const float* W2l  = (const float*)d_in[10];
    const float* b2l  = (const float*)d_in[11];
    const float* W2r  = (const float*)d_in[12];
    const float* b2r  = (const float*)d_in[13];
    const float* We2  = (const float*)d_in[14];
    const float* att2 = (const float*)d_in[15];
    const float* bias2= (const float*)d_in[16];
    const float* alpha= (const float*)d_in[17];
    float* out = (float*)d_out;

    const int F = 128, HC1 = 256, HC2 = 128;
    const int n = in_sizes[0] / F;       // 20000
    const int E = in_sizes[1] / 2;       // 640000

    char* ws = (char*)d_ws;
    size_t off = 0;
    auto alloc = [&](size_t bytes) { size_t p = off; off += (bytes + 255) & ~(size_t)255; return p; };

    int*   deg     = (int*)  (ws + alloc((size_t)n * 4));
    float* ea_sum  = (float*)(ws + alloc((size_t)n * 4));
    int*   row_ptr = (int*)  (ws + alloc((size_t)(n + 1) * 4));
    int*   wptr    = (int*)  (ws + alloc((size_t)n * 4));
    float* ea_loop = (float*)(ws + alloc((size_t)n * 4));
    int*   ssrc    = (int*)  (ws + alloc((size_t)E * 4));
    float* sea     = (float*)(ws + alloc((size_t)E * 4));
    float* xl1     = (float*)(ws + alloc((size_t)n * HC1 * 4));
    float* xr1     = (float*)(ws + alloc((size_t)n * HC1 * 4));
    float* h1      = (float*)(ws + alloc((size_t)n * HC1 * 4));
    // layer-2 buffers alias layer-1 buffers (dead after layer-1 aggregation)
    float* xl2     = xl1;
    float* xr2     = xr1;
    float* h2      = xl1 + (size_t)n * HC2;         // second half of xl1 region
    float* partial = xr1 + (size_t)n * HC2;         // second half of xr1 region
    const int NB_POOL = 256;

    // zero accumulators (re-poisoned to 0xAA before every timed launch)
    hipMemsetAsync(deg, 0, (size_t)n * 4, stream);
    hipMemsetAsync(ea_sum, 0, (size_t)n * 4, stream);

    int tb = 256;
    edge_hist<<<(E + tb - 1) / tb, tb, 0, stream>>>(ei, ea, deg, ea_sum, E);
    scan_deg<<<1, 1024, 0, stream>>>(deg, ea_sum, row_ptr, wptr, ea_loop, n);
    edge_scatter<<<(E + tb - 1) / tb, tb, 0, stream>>>(ei, ea, wptr, ssrc, sea, E);

    // layer 1 projections: [n,128]@[128,256]
    {
        dim3 grid((n + 63) / 64, HC1 / 64);
        gemm_bias<<<grid, 256, 0, stream>>>(x, W1l, b1l, xl1, n, HC1, F);
        gemm_bias<<<grid, 256, 0, stream>>>(x, W1r, b1r, xr1, n, HC1, F);
    }
    gat_agg<256, 32><<<(n + 3) / 4, 256, 0, stream>>>(xl1, xr1, We1, att1, bias1,
                                                      row_ptr, ssrc, sea, ea_loop, h1, n);
    // layer 2 projections: [n,256]@[256,128]
    {
        dim3 grid((n + 63) / 64, HC2 / 64);
        gemm_bias<<<grid, 256, 0, stream>>>(h1, W2l, b2l, xl2, n, HC2, HC1);
        gemm_bias<<<grid, 256, 0, stream>>>(h1, W2r, b2r, xr2, n, HC2, HC1);
    }
    gat_agg<128, 128><<<(n + 3) / 4, 256, 0, stream>>>(xl2, xr2, We2, att2, bias2,
                                                       row_ptr, ssrc, sea, ea_loop, h2, n);

    pool_partial<<<NB_POOL, 128, 0, stream>>>(h2, partial, n);
    pool_final<<<1, 128, 0, stream>>>(partial, NB_POOL, alpha, out, n);
}

// Round 2
// 666.134 us; speedup vs baseline: 1.0311x; 1.0311x over previous
//
#include <hip/hip_runtime.h>
#include <math.h>

#define NEG_SLOPE 0.2f

// ---------------------------------------------------------------------------
// Kernel 1: per-edge histogram: deg[dst]++, ea_sum[dst] += edge_attr[e]
// ---------------------------------------------------------------------------
__global__ void edge_hist(const int* __restrict__ ei, const float* __restrict__ ea,
                          int* __restrict__ deg, float* __restrict__ ea_sum, int E) {
    int e = blockIdx.x * blockDim.x + threadIdx.x;
    if (e < E) {
        int d = ei[E + e];           // dst row of edge_index [2,E]
        atomicAdd(&deg[d], 1);
        atomicAdd(&ea_sum[d], ea[e]);
    }
}

// ---------------------------------------------------------------------------
// Kernel 2: single-block exclusive scan of deg -> row_ptr (and wptr copy),
// plus ea_loop = ea_sum / max(deg,1).  Shfl-based wave scan (16 waves x 64).
// ---------------------------------------------------------------------------
__global__ void scan_deg(const int* __restrict__ deg, const float* __restrict__ ea_sum,
                         int* __restrict__ row_ptr, int* __restrict__ wptr,
                         float* __restrict__ ea_loop, int n) {
    __shared__ int wsum[16];
    __shared__ int carry_s;
    int tid = threadIdx.x;
    int wid = tid >> 6, lane = tid & 63;
    if (tid == 0) carry_s = 0;
    __syncthreads();
    for (int base = 0; base < n; base += 1024) {
        int i = base + tid;
        int v = (i < n) ? deg[i] : 0;
        // inclusive wave scan
        int s = v;
#pragma unroll
        for (int off = 1; off < 64; off <<= 1) {
            int t = __shfl_up(s, off, 64);
            if (lane >= off) s += t;
        }
        if (lane == 63) wsum[wid] = s;
        __syncthreads();
        if (tid < 16) {
            int sc = wsum[tid];
#pragma unroll
            for (int off = 1; off < 16; off <<= 1) {
                int u = __shfl_up(sc, off, 16);
                if (tid >= off) sc += u;
            }
            wsum[tid] = sc;
        }
        __syncthreads();
        int prev = (wid > 0) ? wsum[wid - 1] : 0;
        int carry = carry_s;
        int incl = carry + prev + s;
        if (i < n) {
            int excl = incl - v;
            row_ptr[i] = excl;
            wptr[i]    = excl;
            ea_loop[i] = ea_sum[i] / fmaxf((float)v, 1.0f);
        }
        __syncthreads();
        if (tid == 0) carry_s = carry + wsum[15];
        __syncthreads();
    }
    if (tid == 0) row_ptr[n] = carry_s;
}

// ---------------------------------------------------------------------------
// Kernel 3: scatter edges into CSR order (bucket order nondeterministic; sums
// are order-insensitive up to fp rounding which is << threshold).
// ---------------------------------------------------------------------------
__global__ void edge_scatter(const int* __restrict__ ei, const float* __restrict__ ea,
                             int* __restrict__ wptr, int* __restrict__ ssrc,
                             float* __restrict__ sea, int E) {
    int e = blockIdx.x * blockDim.x + threadIdx.x;
    if (e < E) {
        int d = ei[E + e];
        int pos = atomicAdd(&wptr[d], 1);
        ssrc[pos] = ei[e];
        sea[pos]  = ea[e];
    }
}

// ---------------------------------------------------------------------------
// Kernel 4: fp32 GEMM + bias: C[M,N] = A[M,K] @ B[K,N] + bias[N]
// 64x64 tile, BK=16, 256 threads, 4x4 microtile.
// ---------------------------------------------------------------------------
__global__ void gemm_bias(const float* __restrict__ A, const float* __restrict__ B,
                          const float* __restrict__ bias, float* __restrict__ C,
                          int M, int N, int K) {
    __shared__ float As[16][68];   // [k][m], padded
    __shared__ float Bs[16][68];   // [k][n], padded
    int tid = threadIdx.x;
    int tx = tid & 15, ty = tid >> 4;
    int m0 = blockIdx.x * 64, n0 = blockIdx.y * 64;
    float acc[4][4] = {};
    for (int kk = 0; kk < K; kk += 16) {
        for (int t = tid; t < 1024; t += 256) {
            int m = t >> 4, k = t & 15;
            int gm = m0 + m;
            As[k][m] = (gm < M) ? A[(size_t)gm * K + kk + k] : 0.0f;
        }
        for (int t = tid; t < 1024; t += 256) {
            int k = t >> 6, n = t & 63;
            Bs[k][n] = B[(size_t)(kk + k) * N + n0 + n];
        }
        __syncthreads();
#pragma unroll
        for (int k = 0; k < 16; ++k) {
            float a[4], b[4];
#pragma unroll
            for (int i = 0; i < 4; ++i) a[i] = As[k][ty * 4 + i];
#pragma unroll
            for (int j = 0; j < 4; ++j) b[j] = Bs[k][tx * 4 + j];
#pragma unroll
            for (int i = 0; i < 4; ++i)
#pragma unroll
                for (int j = 0; j < 4; ++j) acc[i][j] += a[i] * b[j];
        }
        __syncthreads();
    }
#pragma unroll
    for (int i = 0; i < 4; ++i) {
        int gm = m0 + ty * 4 + i;
        if (gm < M) {
#pragma unroll
            for (int j = 0; j < 4; ++j) {
                int gn = n0 + tx * 4 + j;
                C[(size_t)gm * N + gn] = acc[i][j] + bias[gn];
            }
        }
    }
}

// ---------------------------------------------------------------------------
// vector row load helper
// ---------------------------------------------------------------------------
template <int NV>
__device__ __forceinline__ void ld_row(float* r, const float* p) {
    if constexpr (NV == 4) {
        float4 t = *(const float4*)p;
        r[0] = t.x; r[1] = t.y; r[2] = t.z; r[3] = t.w;
    } else {
        float2 t = *(const float2*)p;
        r[0] = t.x; r[1] = t.y;
    }
}

// ---------------------------------------------------------------------------
// Kernel 5: fused GATv2 gather + score + softmax + aggregate + relu.
// One wave (64 lanes) per destination node; 4 nodes per 256-thread block.
// Lane owns NV = HC/64 contiguous channels (never crossing a head boundary).
// Scores are statistically tiny (|s| < ~3), so exp(s)/sum(exp(s)) without the
// max-subtraction is numerically safe and removes the loop-carried rescale
// dependency.  Edge loop is software-pipelined: gather for edge e+1 is issued
// before computing edge e; edge indices are prefetched 2 deep.
// HC=256,C=32 (layer1: NV=4, reduce width 8) | HC=128,C=128 (layer2: NV=2, w64)
// ---------------------------------------------------------------------------
template <int HC, int C>
__global__ void __launch_bounds__(256)
gat_agg(const float* __restrict__ xl, const float* __restrict__ xr,
        const float* __restrict__ We, const float* __restrict__ att,
        const float* __restrict__ bias,
        const int* __restrict__ row_ptr, const int* __restrict__ ssrc,
        const float* __restrict__ sea, const float* __restrict__ ea_loop,
        float* __restrict__ out, int n) {
    constexpr int NV = HC / 64;      // channels per lane
    constexpr int G  = C / NV;       // reduction group width (lanes per head)
    int wave = threadIdx.x >> 6;
    int lane = threadIdx.x & 63;
    int node = blockIdx.x * 4 + wave;
    if (node >= n) return;

    float xr_r[NV], We_r[NV], att_r[NV], o[NV];
    ld_row<NV>(xr_r, xr + (size_t)node * HC + lane * NV);
    ld_row<NV>(We_r, We + lane * NV);
    ld_row<NV>(att_r, att + lane * NV);
#pragma unroll
    for (int j = 0; j < NV; ++j) o[j] = 0.0f;
    float l = 0.0f;

    int start = row_ptr[node], end = row_ptr[node + 1];
    float ea_l = ea_loop[node];

    // pipeline: A = edge e (row gathered), B = edge e+1 (index only)
    int srcA, srcB = 0;
    float wA, wB = 0.0f;
    if (start < end) { srcA = ssrc[start]; wA = sea[start]; }
    else             { srcA = node;        wA = ea_l;       }
    if (start + 1 <= end) {
        if (start + 1 < end) { srcB = ssrc[start + 1]; wB = sea[start + 1]; }
        else                 { srcB = node;            wB = ea_l;           }
    }
    float xA[NV];
    ld_row<NV>(xA, xl + (size_t)srcA * HC + lane * NV);

    for (int e = start; e <= end; ++e) {
        bool has_next = (e + 1 <= end);
        float xB[NV];
        if (has_next) ld_row<NV>(xB, xl + (size_t)srcB * HC + lane * NV);

        float vs = 0.0f;
#pragma unroll
        for (int j = 0; j < NV; ++j) {
            float t  = fmaf(wA, We_r[j], xr_r[j]);
            float mm = xA[j] + t;
            float lr = fmaxf(mm, 0.0f) + NEG_SLOPE * fminf(mm, 0.0f);
            vs = fmaf(lr, att_r[j], vs);
        }
#pragma unroll
        for (int off = G / 2; off > 0; off >>= 1) vs += __shfl_xor(vs, off, G);
        float pr = __expf(vs);
        l += pr;
#pragma unroll
        for (int j = 0; j < NV; ++j) o[j] = fmaf(pr, xA[j], o[j]);

        if (has_next) {
#pragma unroll
            for (int j = 0; j < NV; ++j) xA[j] = xB[j];
            srcA = srcB; wA = wB;
            int e2 = e + 2;
            if (e2 <= end) {
                if (e2 < end) { srcB = ssrc[e2]; wB = sea[e2]; }
                else          { srcB = node;     wB = ea_l;    }
            }
        }
    }

    float inv = 1.0f / (l + 1e-16f);
    float b_r[NV];
    ld_row<NV>(b_r, bias + lane * NV);
    float* op = out + (size_t)node * HC + lane * NV;
    if constexpr (NV == 4) {
        float4 t;
        t.x = fmaxf(o[0] * inv + b_r[0], 0.0f);
        t.y = fmaxf(o[1] * inv + b_r[1], 0.0f);
        t.z = fmaxf(o[2] * inv + b_r[2], 0.0f);
        t.w = fmaxf(o[3] * inv + b_r[3], 0.0f);
        *(float4*)op = t;
    } else {
        float2 t;
        t.x = fmaxf(o[0] * inv + b_r[0], 0.0f);
        t.y = fmaxf(o[1] * inv + b_r[1], 0.0f);
        *(float2*)op = t;
    }
}

// ---------------------------------------------------------------------------
// Kernel 6: column partial sums of h2 [n,128] -> partial[gridDim.x*128]
// ---------------------------------------------------------------------------
__global__ void pool_partial(const float* __restrict__ h2, float* __restrict__ partial, int n) {
    int t = threadIdx.x;          // 0..127
    float s = 0.0f;
    for (int r = blockIdx.x; r < n; r += gridDim.x) s += h2[(size_t)r * 128 + t];
    partial[blockIdx.x * 128 + t] = s;
}

// ---------------------------------------------------------------------------
// Kernel 7: finish pooling, softmax over 128, sigmoid(alpha). 1 block x 128.
// ---------------------------------------------------------------------------
__global__ void pool_final(const float* __restrict__ partial, int nb,
                           const float* __restrict__ alpha_in,
                           float* __restrict__ out, int n) {
    __shared__ float red[4];
    int t = threadIdx.x;          // 0..127
    float s = 0.0f;
    for (int b = 0; b < nb; ++b) s += partial[b * 128 + t];
    float mean = s / (float)n;
    float mx = mean;
#pragma unroll
    for (int off = 32; off > 0; off >>= 1) mx = fmaxf(mx, __shfl_xor(mx, off, 64));
    if ((t & 63) == 0) red[t >> 6] = mx;
    __syncthreads();
    mx = fmaxf(red[0], red[1]);
    float ex = __expf(mean - mx);
    float sm = ex;
#pragma unroll
    for (int off = 32; off > 0; off >>= 1) sm += __shfl_xor(sm, off, 64);
    if ((t & 63) == 0) red[2 + (t >> 6)] = sm;
    __syncthreads();
    sm = red[2] + red[3];
    out[t] = ex / sm;
    if (t == 0) out[128] = 1.0f / (1.0f + __expf(-alpha_in[0]));
}

// ---------------------------------------------------------------------------
extern "C" void kernel_launch(void* const* d_in, const int* in_sizes, int n_in,
                              void* d_out, int out_size, void* d_ws, size_t ws_size,
                              hipStream_t stream) {
    const float* x    = (const float*)d_in[0];
    const int*   ei   = (const int*)d_in[1];    // [2,E] int32
    const float* ea   = (const float*)d_in[2];
    const float* W1l  = (const float*)d_in[3];
    const float* b1l  = (const float*)d_in[4];
    const float* W1r  = (const float*)d_in[5];
    const float* b1r  = (const float*)d_in[6];
    const float* We1  = (const float*)d_in[7];
    const float* att1 = (const float*)d_in[8];
    const float* bias1= (const float*)d_in[9];
    const float* W2l  = (const float*)d_in[10];
    const float* b2l  = (const float*)d_in[11];
    const float* W2r  = (const float*)d_in[12];
    const float* b2r  = (const float*)d_in[13];
    const float* We2  = (const float*)d_in[14];
    const float* att2 = (const float*)d_in[15];
    const float* bias2= (const float*)d_in[16];
    const float* alpha= (const float*)d_in[17];
    float* out = (float*)d_out;

    const int F = 128, HC1 = 256, HC2 = 128;
    const int n = in_sizes[0] / F;       // 20000
    const int E = in_sizes[1] / 2;       // 640000

    char* ws = (char*)d_ws;
    size_t off = 0;
    auto alloc = [&](size_t bytes) { size_t p = off; off += (bytes + 255) & ~(size_t)255; return p; };

    int*   deg     = (int*)  (ws + alloc((size_t)n * 4));
    float* ea_sum  = (float*)(ws + alloc((size_t)n * 4));
    int*   row_ptr = (int*)  (ws + alloc((size_t)(n + 1) * 4));
    int*   wptr    = (int*)  (ws + alloc((size_t)n * 4));
    float* ea_loop = (float*)(ws + alloc((size_t)n * 4));
    int*   ssrc    = (int*)  (ws + alloc((size_t)E * 4));
    float* sea     = (float*)(ws + alloc((size_t)E * 4));
    float* xl1     = (float*)(ws + alloc((size_t)n * HC1 * 4));
    float* xr1     = (float*)(ws + alloc((size_t)n * HC1 * 4));
    float* h1      = (float*)(ws + alloc((size_t)n * HC1 * 4));
    // layer-2 buffers alias layer-1 buffers (dead after layer-1 aggregation)
    float* xl2     = xl1;
    float* xr2     = xr1;
    float* h2      = xl1 + (size_t)n * HC2;         // second half of xl1 region
    float* partial = xr1 + (size_t)n * HC2;         // second half of xr1 region
    const int NB_POOL = 256;

    // zero accumulators (re-poisoned to 0xAA before every timed launch)
    hipMemsetAsync(deg, 0, (size_t)n * 4, stream);
    hipMemsetAsync(ea_sum, 0, (size_t)n * 4, stream);

    int tb = 256;
    edge_hist<<<(E + tb - 1) / tb, tb, 0, stream>>>(ei, ea, deg, ea_sum, E);
    scan_deg<<<1, 1024, 0, stream>>>(deg, ea_sum, row_ptr, wptr, ea_loop, n);
    edge_scatter<<<(E + tb - 1) / tb, tb, 0, stream>>>(ei, ea, wptr, ssrc, sea, E);

    // layer 1 projections: [n,128]@[128,256]
    {
        dim3 grid((n + 63) / 64, HC1 / 64);
        gemm_bias<<<grid, 256, 0, stream>>>(x, W1l, b1l, xl1, n, HC1, F);
        gemm_bias<<<grid, 256, 0, stream>>>(x, W1r, b1r, xr1, n, HC1, F);
    }
    gat_agg<256, 32><<<(n + 3) / 4, 256, 0, stream>>>(xl1, xr1, We1, att1, bias1,
                                                      row_ptr, ssrc, sea, ea_loop, h1, n);
    // layer 2 projections: [n,256]@[256,128]
    {
        dim3 grid((n + 63) / 64, HC2 / 64);
        gemm_bias<<<grid, 256, 0, stream>>>(h1, W2l, b2l, xl2, n, HC2, HC1);
        gemm_bias<<<grid, 256, 0, stream>>>(h1, W2r, b2r, xr2, n, HC2, HC1);
    }
    gat_agg<128, 128><<<(n + 3) / 4, 256, 0, stream>>>(xl2, xr2, We2, att2, bias2,
                                                       row_ptr, ssrc, sea, ea_loop, h2, n);

    pool_partial<<<NB_POOL, 128, 0, stream>>>(h2, partial, n);
    pool_final<<<1, 128, 0, stream>>>(partial, NB_POOL, alpha, out, n);
}

// Round 3
// 505.708 us; speedup vs baseline: 1.3582x; 1.3172x over previous
//
#include <hip/hip_runtime.h>
#include <math.h>

#define NEG_SLOPE 0.2f

typedef __attribute__((ext_vector_type(8))) short short8;   // 8 bf16 (4 VGPRs)
typedef __attribute__((ext_vector_type(4))) float f32x4;

__device__ __forceinline__ unsigned short f2bf(float f) {
    unsigned int u = __float_as_uint(f);
    unsigned int r = (u + 0x7fffu + ((u >> 16) & 1u)) >> 16;   // RNE
    return (unsigned short)r;
}
__device__ __forceinline__ void bf2f(unsigned int u, float& a, float& b) {
    a = __uint_as_float(u << 16);
    b = __uint_as_float(u & 0xffff0000u);
}

// ---------------------------------------------------------------------------
// Kernel 1: per-edge histogram: deg[dst]++, ea_sum[dst] += edge_attr[e]
// ---------------------------------------------------------------------------
__global__ void edge_hist(const int* __restrict__ ei, const float* __restrict__ ea,
                          int* __restrict__ deg, float* __restrict__ ea_sum, int E) {
    int e = blockIdx.x * blockDim.x + threadIdx.x;
    if (e < E) {
        int d = ei[E + e];
        atomicAdd(&deg[d], 1);
        atomicAdd(&ea_sum[d], ea[e]);
    }
}

// ---------------------------------------------------------------------------
// Kernel 2: single-block scan of deg -> row_ptr, ea_loop = ea_sum/max(deg,1)
// ---------------------------------------------------------------------------
__global__ void scan_deg(const int* __restrict__ deg, const float* __restrict__ ea_sum,
                         int* __restrict__ row_ptr, int* __restrict__ wptr,
                         float* __restrict__ ea_loop, int n) {
    __shared__ int wsum[16];
    __shared__ int carry_s;
    int tid = threadIdx.x;
    int wid = tid >> 6, lane = tid & 63;
    if (tid == 0) carry_s = 0;
    __syncthreads();
    for (int base = 0; base < n; base += 1024) {
        int i = base + tid;
        int v = (i < n) ? deg[i] : 0;
        int s = v;
#pragma unroll
        for (int off = 1; off < 64; off <<= 1) {
            int t = __shfl_up(s, off, 64);
            if (lane >= off) s += t;
        }
        if (lane == 63) wsum[wid] = s;
        __syncthreads();
        if (tid < 16) {
            int sc = wsum[tid];
#pragma unroll
            for (int off = 1; off < 16; off <<= 1) {
                int u = __shfl_up(sc, off, 16);
                if (tid >= off) sc += u;
            }
            wsum[tid] = sc;
        }
        __syncthreads();
        int prev = (wid > 0) ? wsum[wid - 1] : 0;
        int carry = carry_s;
        int incl = carry + prev + s;
        if (i < n) {
            int excl = incl - v;
            row_ptr[i] = excl;
            wptr[i]    = excl;
            ea_loop[i] = ea_sum[i] / fmaxf((float)v, 1.0f);
        }
        __syncthreads();
        if (tid == 0) carry_s = carry + wsum[15];
        __syncthreads();
    }
    if (tid == 0) row_ptr[n] = carry_s;
}

// ---------------------------------------------------------------------------
// Kernel 3: scatter edges into CSR order
// ---------------------------------------------------------------------------
__global__ void edge_scatter(const int* __restrict__ ei, const float* __restrict__ ea,
                             int* __restrict__ wptr, int* __restrict__ ssrc,
                             float* __restrict__ sea, int E) {
    int e = blockIdx.x * blockDim.x + threadIdx.x;
    if (e < E) {
        int d = ei[E + e];
        int pos = atomicAdd(&wptr[d], 1);
        ssrc[pos] = ei[e];
        sea[pos]  = ea[e];
    }
}

// ---------------------------------------------------------------------------
// Conversion kernels: fp32 -> bf16 (elementwise), fp32 [K][N] -> bf16 [N][K]
// ---------------------------------------------------------------------------
__global__ void cvt_bf16(const float* __restrict__ in, unsigned short* __restrict__ out, int sz) {
    int i = blockIdx.x * blockDim.x + threadIdx.x;
    if (i < sz) out[i] = f2bf(in[i]);
}
__global__ void tr_cvt_bf16(const float* __restrict__ in, unsigned short* __restrict__ out,
                            int K, int N) {
    int i = blockIdx.x * blockDim.x + threadIdx.x;
    if (i < K * N) {
        int k = i / N, nn = i - k * N;
        out[nn * K + k] = f2bf(in[i]);
    }
}

// ---------------------------------------------------------------------------
// Kernel 4: bf16 MFMA GEMM + bias: C[M,N] = A[M,K] @ B[K,N] + bias, C bf16.
// B passed pre-transposed as Bt[N][K].  64x64 block tile, BK=32, 4 waves,
// wave-tile 16x64 (4x mfma_f32_16x16x32_bf16).
// A-frag: lane holds A[m=lane&15][k=(lane>>4)*8+j]; B-frag: Bt row n likewise;
// D: col=lane&15, row=(lane>>4)*4+reg  [m89/m91-verified layouts]
// ---------------------------------------------------------------------------
__global__ void __launch_bounds__(256)
gemm_bf16(const unsigned short* __restrict__ A, const unsigned short* __restrict__ Bt,
          const float* __restrict__ bias, unsigned short* __restrict__ C,
          int M, int N, int K) {
    __shared__ __attribute__((aligned(16))) unsigned short As[64 * 40];  // stride 40 elts (80B)
    __shared__ __attribute__((aligned(16))) unsigned short Bs[64 * 40];
    int tid  = threadIdx.x;
    int wave = tid >> 6, lane = tid & 63;
    int m0 = blockIdx.x * 64, n0 = blockIdx.y * 64;
    int row = tid >> 2, kg = (tid & 3) * 8;   // staging: 16B per thread per tile

    f32x4 acc[4] = {};
    for (int kk = 0; kk < K; kk += 32) {
        int gm = m0 + row;
        uint4 av;
        if (gm < M) av = *(const uint4*)(A + (size_t)gm * K + kk + kg);
        else        av = make_uint4(0, 0, 0, 0);
        *(uint4*)&As[row * 40 + kg] = av;
        uint4 bv = *(const uint4*)(Bt + (size_t)(n0 + row) * K + kk + kg);
        *(uint4*)&Bs[row * 40 + kg] = bv;
        __syncthreads();
        short8 a = *(const short8*)&As[(wave * 16 + (lane & 15)) * 40 + (lane >> 4) * 8];
#pragma unroll
        for (int g = 0; g < 4; ++g) {
            short8 b = *(const short8*)&Bs[(g * 16 + (lane & 15)) * 40 + (lane >> 4) * 8];
            acc[g] = __builtin_amdgcn_mfma_f32_16x16x32_bf16(a, b, acc[g], 0, 0, 0);
        }
        __syncthreads();
    }
#pragma unroll
    for (int g = 0; g < 4; ++g) {
        int col = n0 + g * 16 + (lane & 15);
        float bs = bias[col];
#pragma unroll
        for (int r = 0; r < 4; ++r) {
            int grow = m0 + wave * 16 + (lane >> 4) * 4 + r;
            if (grow < M) C[(size_t)grow * N + col] = f2bf(acc[g][r] + bs);
        }
    }
}

// ---------------------------------------------------------------------------
// fp32 vector row-load helper (small param arrays)
// ---------------------------------------------------------------------------
template <int NV>
__device__ __forceinline__ void ld_row(float* r, const float* p) {
    if constexpr (NV == 4) {
        float4 t = *(const float4*)p;
        r[0] = t.x; r[1] = t.y; r[2] = t.z; r[3] = t.w;
    } else {
        float2 t = *(const float2*)p;
        r[0] = t.x; r[1] = t.y;
    }
}
template <int NV>
__device__ __forceinline__ uint2 ld_bf(const unsigned short* base, size_t off) {
    if constexpr (NV == 4) return *(const uint2*)(base + off);
    else { uint2 r; r.x = *(const unsigned int*)(base + off); r.y = 0; return r; }
}

// ---------------------------------------------------------------------------
// Kernel 5: fused GATv2 gather(bf16) + score + softmax + aggregate + relu.
// One wave per destination node; depth-2 gather pipeline (2 rows in flight).
// HC=256,C=32 (layer1: NV=4, G=8, out bf16) | HC=128,C=128 (layer2: NV=2, G=64, out fp32)
// ---------------------------------------------------------------------------
template <int HC, int C, bool OUT_BF16>
__global__ void __launch_bounds__(256)
gat_agg(const unsigned short* __restrict__ xl, const unsigned short* __restrict__ xr,
        const float* __restrict__ We, const float* __restrict__ att,
        const float* __restrict__ bias,
        const int* __restrict__ row_ptr, const int* __restrict__ ssrc,
        const float* __restrict__ sea, const float* __restrict__ ea_loop,
        void* __restrict__ out, int n) {
    constexpr int NV = HC / 64;
    constexpr int G  = C / NV;
    int wave = threadIdx.x >> 6;
    int lane = threadIdx.x & 63;
    int node = blockIdx.x * 4 + wave;
    if (node >= n) return;

    float xr_r[NV], We_r[NV], att_r[NV], o[NV];
    {
        uint2 u = ld_bf<NV>(xr, (size_t)node * HC + lane * NV);
        if constexpr (NV == 4) { bf2f(u.x, xr_r[0], xr_r[1]); bf2f(u.y, xr_r[2], xr_r[3]); }
        else                   { bf2f(u.x, xr_r[0], xr_r[1]); }
    }
    ld_row<NV>(We_r, We + lane * NV);
    ld_row<NV>(att_r, att + lane * NV);
#pragma unroll
    for (int j = 0; j < NV; ++j) o[j] = 0.0f;
    float l = 0.0f;

    int start = row_ptr[node], end = row_ptr[node + 1];
    float ea_l = ea_loop[node];

    int srcA = node, srcB = node;
    float wA = ea_l, wB = ea_l;
    if (start < end) { srcA = ssrc[start]; wA = sea[start]; }
    if (start + 1 <= end) {
        if (start + 1 < end) { srcB = ssrc[start + 1]; wB = sea[start + 1]; }
    }
    uint2 xA = ld_bf<NV>(xl, (size_t)srcA * HC + lane * NV);
    uint2 xB = (start + 1 <= end) ? ld_bf<NV>(xl, (size_t)srcB * HC + lane * NV) : xA;

    for (int e = start; e <= end; ++e) {
        uint2 xC; float wC = 0.0f;
        bool hasC = (e + 2 <= end);
        if (hasC) {
            int srcC = node; wC = ea_l;
            if (e + 2 < end) { srcC = ssrc[e + 2]; wC = sea[e + 2]; }
            xC = ld_bf<NV>(xl, (size_t)srcC * HC + lane * NV);
        }

        float xf[NV];
        if constexpr (NV == 4) { bf2f(xA.x, xf[0], xf[1]); bf2f(xA.y, xf[2], xf[3]); }
        else                   { bf2f(xA.x, xf[0], xf[1]); }

        float vs = 0.0f;
#pragma unroll
        for (int j = 0; j < NV; ++j) {
            float t  = fmaf(wA, We_r[j], xr_r[j]);
            float mm = xf[j] + t;
            float lr = fmaxf(mm, 0.0f) + NEG_SLOPE * fminf(mm, 0.0f);
            vs = fmaf(lr, att_r[j], vs);
        }
#pragma unroll
        for (int off = G / 2; off > 0; off >>= 1) vs += __shfl_xor(vs, off, G);
        float pr = __expf(vs);
        l += pr;
#pragma unroll
        for (int j = 0; j < NV; ++j) o[j] = fmaf(pr, xf[j], o[j]);

        xA = xB; wA = wB;
        if (hasC) { xB = xC; wB = wC; }
    }

    float inv = 1.0f / (l + 1e-16f);
    float b_r[NV];
    ld_row<NV>(b_r, bias + lane * NV);
    float v[NV];
#pragma unroll
    for (int j = 0; j < NV; ++j) v[j] = fmaxf(o[j] * inv + b_r[j], 0.0f);

    if constexpr (OUT_BF16) {
        unsigned short* op = (unsigned short*)out + (size_t)node * HC + lane * NV;
        if constexpr (NV == 4) {
            uint2 t;
            t.x = (unsigned int)f2bf(v[0]) | ((unsigned int)f2bf(v[1]) << 16);
            t.y = (unsigned int)f2bf(v[2]) | ((unsigned int)f2bf(v[3]) << 16);
            *(uint2*)op = t;
        } else {
            unsigned int t = (unsigned int)f2bf(v[0]) | ((unsigned int)f2bf(v[1]) << 16);
            *(unsigned int*)op = t;
        }
    } else {
        float* op = (float*)out + (size_t)node * HC + lane * NV;
        if constexpr (NV == 4) { *(float4*)op = make_float4(v[0], v[1], v[2], v[3]); }
        else                   { *(float2*)op = make_float2(v[0], v[1]); }
    }
}

// ---------------------------------------------------------------------------
// Kernel 6: column partial sums of h2 [n,128] -> partial[gridDim.x*128]
// ---------------------------------------------------------------------------
__global__ void pool_partial(const float* __restrict__ h2, float* __restrict__ partial, int n) {
    int t = threadIdx.x;
    float s = 0.0f;
    for (int r = blockIdx.x; r < n; r += gridDim.x) s += h2[(size_t)r * 128 + t];
    partial[blockIdx.x * 128 + t] = s;
}

// ---------------------------------------------------------------------------
// Kernel 7: finish pooling, softmax over 128, sigmoid(alpha). 1 block x 128.
// ---------------------------------------------------------------------------
__global__ void pool_final(const float* __restrict__ partial, int nb,
                           const float* __restrict__ alpha_in,
                           float* __restrict__ out, int n) {
    __shared__ float red[4];
    int t = threadIdx.x;
    float s = 0.0f;
    for (int b = 0; b < nb; ++b) s += partial[b * 128 + t];
    float mean = s / (float)n;
    float mx = mean;
#pragma unroll
    for (int off = 32; off > 0; off >>= 1) mx = fmaxf(mx, __shfl_xor(mx, off, 64));
    if ((t & 63) == 0) red[t >> 6] = mx;
    __syncthreads();
    mx = fmaxf(red[0], red[1]);
    float ex = __expf(mean - mx);
    float sm = ex;
#pragma unroll
    for (int off = 32; off > 0; off >>= 1) sm += __shfl_xor(sm, off, 64);
    if ((t & 63) == 0) red[2 + (t >> 6)] = sm;
    __syncthreads();
    sm = red[2] + red[3];
    out[t] = ex / sm;
    if (t == 0) out[128] = 1.0f / (1.0f + __expf(-alpha_in[0]));
}

// ---------------------------------------------------------------------------
extern "C" void kernel_launch(void* const* d_in, const int* in_sizes, int n_in,
                              void* d_out, int out_size, void* d_ws, size_t ws_size,
                              hipStream_t stream) {
    const float* x    = (const float*)d_in[0];
    const int*   ei   = (const int*)d_in[1];
    const float* ea   = (const float*)d_in[2];
    const float* W1l  = (const float*)d_in[3];
    const float* b1l  = (const float*)d_in[4];
    const float* W1r  = (const float*)d_in[5];
    const float* b1r  = (const float*)d_in[6];
    const float* We1  = (const float*)d_in[7];
    const float* att1 = (const float*)d_in[8];
    const float* bias1= (const float*)d_in[9];
    const float* W2l  = (const float*)d_in[10];
    const float* b2l  = (const float*)d_in[11];
    const float* W2r  = (const float*)d_in[12];
    const float* b2r  = (const float*)d_in[13];
    const float* We2  = (const float*)d_in[14];
    const float* att2 = (const float*)d_in[15];
    const float* bias2= (const float*)d_in[16];
    const float* alpha= (const float*)d_in[17];
    float* out = (float*)d_out;

    const int F = 128, HC1 = 256, HC2 = 128;
    const int n = in_sizes[0] / F;       // 20000
    const int E = in_sizes[1] / 2;       // 640000

    char* ws = (char*)d_ws;
    size_t off = 0;
    auto alloc = [&](size_t bytes) { size_t p = off; off += (bytes + 255) & ~(size_t)255; return p; };

    int*   deg     = (int*)  (ws + alloc((size_t)n * 4));
    float* ea_sum  = (float*)(ws + alloc((size_t)n * 4));
    int*   row_ptr = (int*)  (ws + alloc((size_t)(n + 1) * 4));
    int*   wptr    = (int*)  (ws + alloc((size_t)n * 4));
    float* ea_loop = (float*)(ws + alloc((size_t)n * 4));
    int*   ssrc    = (int*)  (ws + alloc((size_t)E * 4));
    float* sea     = (float*)(ws + alloc((size_t)E * 4));
    unsigned short* xb    = (unsigned short*)(ws + alloc((size_t)n * F * 2));
    unsigned short* W1lt  = (unsigned short*)(ws + alloc((size_t)F * HC1 * 2));
    unsigned short* W1rt  = (unsigned short*)(ws + alloc((size_t)F * HC1 * 2));
    unsigned short* W2lt  = (unsigned short*)(ws + alloc((size_t)HC1 * HC2 * 2));
    unsigned short* W2rt  = (unsigned short*)(ws + alloc((size_t)HC1 * HC2 * 2));
    unsigned short* xl1   = (unsigned short*)(ws + alloc((size_t)n * HC1 * 2));
    unsigned short* xr1   = (unsigned short*)(ws + alloc((size_t)n * HC1 * 2));
    unsigned short* h1    = (unsigned short*)(ws + alloc((size_t)n * HC1 * 2));
    float* h2      = (float*)(ws + alloc((size_t)n * HC2 * 4));
    float* partial = (float*)(ws + alloc((size_t)256 * 128 * 4));
    // layer-2 projections alias layer-1 buffers (dead after layer-1 gat)
    unsigned short* xl2 = xl1;
    unsigned short* xr2 = xr1;
    const int NB_POOL = 256;

    hipMemsetAsync(deg, 0, (size_t)n * 4, stream);
    hipMemsetAsync(ea_sum, 0, (size_t)n * 4, stream);

    int tb = 256;
    edge_hist<<<(E + tb - 1) / tb, tb, 0, stream>>>(ei, ea, deg, ea_sum, E);
    scan_deg<<<1, 1024, 0, stream>>>(deg, ea_sum, row_ptr, wptr, ea_loop, n);
    edge_scatter<<<(E + tb - 1) / tb, tb, 0, stream>>>(ei, ea, wptr, ssrc, sea, E);

    // conversions
    cvt_bf16<<<(n * F + tb - 1) / tb, tb, 0, stream>>>(x, xb, n * F);
    tr_cvt_bf16<<<(F * HC1 + tb - 1) / tb, tb, 0, stream>>>(W1l, W1lt, F, HC1);
    tr_cvt_bf16<<<(F * HC1 + tb - 1) / tb, tb, 0, stream>>>(W1r, W1rt, F, HC1);
    tr_cvt_bf16<<<(HC1 * HC2 + tb - 1) / tb, tb, 0, stream>>>(W2l, W2lt, HC1, HC2);
    tr_cvt_bf16<<<(HC1 * HC2 + tb - 1) / tb, tb, 0, stream>>>(W2r, W2rt, HC1, HC2);

    // layer 1 projections: [n,128]@[128,256] (bf16 MFMA)
    {
        dim3 grid((n + 63) / 64, HC1 / 64);
        gemm_bf16<<<grid, 256, 0, stream>>>(xb, W1lt, b1l, xl1, n, HC1, F);
        gemm_bf16<<<grid, 256, 0, stream>>>(xb, W1rt, b1r, xr1, n, HC1, F);
    }
    gat_agg<256, 32, true><<<(n + 3) / 4, 256, 0, stream>>>(xl1, xr1, We1, att1, bias1,
                                                            row_ptr, ssrc, sea, ea_loop, h1, n);
    // layer 2 projections: [n,256]@[256,128]
    {
        dim3 grid((n + 63) / 64, HC2 / 64);
        gemm_bf16<<<grid, 256, 0, stream>>>(h1, W2lt, b2l, xl2, n, HC2, HC1);
        gemm_bf16<<<grid, 256, 0, stream>>>(h1, W2rt, b2r, xr2, n, HC2, HC1);
    }
    gat_agg<128, 128, false><<<(n + 3) / 4, 256, 0, stream>>>(xl2, xr2, We2, att2, bias2,
                                                              row_ptr, ssrc, sea, ea_loop, h2, n);

    pool_partial<<<NB_POOL, 128, 0, stream>>>(h2, partial, n);
    pool_final<<<1, 128, 0, stream>>>(partial, NB_POOL, alpha, out, n);
}

// Round 5
// 469.918 us; speedup vs baseline: 1.4616x; 1.0762x over previous
//
#include <hip/hip_runtime.h>
#include <math.h>

#define NEG_SLOPE 0.2f

typedef __attribute__((ext_vector_type(8))) short short8;   // 8 bf16 (4 VGPRs)
typedef __attribute__((ext_vector_type(4))) float f32x4;

__device__ __forceinline__ unsigned short f2bf(float f) {
    unsigned int u = __float_as_uint(f);
    unsigned int r = (u + 0x7fffu + ((u >> 16) & 1u)) >> 16;   // RNE
    return (unsigned short)r;
}
__device__ __forceinline__ void bf2f(unsigned int u, float& a, float& b) {
    a = __uint_as_float(u << 16);
    b = __uint_as_float(u & 0xffff0000u);
}
// DPP-based partial-sum step: v += dpp_perm(v). ctrl must be a compile-time
// immediate -> template parameter.
template <int CTRL>
__device__ __forceinline__ float dpp_add(float v) {
    int t = __builtin_amdgcn_update_dpp(0, __float_as_int(v), CTRL, 0xF, 0xF, true);
    return v + __int_as_float(t);
}

// ---------------------------------------------------------------------------
// Kernel 1: per-edge histogram: deg[dst]++, ea_sum[dst] += edge_attr[e]
// ---------------------------------------------------------------------------
__global__ void edge_hist(const int* __restrict__ ei, const float* __restrict__ ea,
                          int* __restrict__ deg, float* __restrict__ ea_sum, int E) {
    int e = blockIdx.x * blockDim.x + threadIdx.x;
    if (e < E) {
        int d = ei[E + e];
        atomicAdd(&deg[d], 1);
        atomicAdd(&ea_sum[d], ea[e]);
    }
}

// ---------------------------------------------------------------------------
// Kernel 2: single-block scan of deg -> row_ptr, ea_loop = ea_sum/max(deg,1)
// ---------------------------------------------------------------------------
__global__ void scan_deg(const int* __restrict__ deg, const float* __restrict__ ea_sum,
                         int* __restrict__ row_ptr, int* __restrict__ wptr,
                         float* __restrict__ ea_loop, int n) {
    __shared__ int wsum[16];
    __shared__ int carry_s;
    int tid = threadIdx.x;
    int wid = tid >> 6, lane = tid & 63;
    if (tid == 0) carry_s = 0;
    __syncthreads();
    for (int base = 0; base < n; base += 1024) {
        int i = base + tid;
        int v = (i < n) ? deg[i] : 0;
        int s = v;
#pragma unroll
        for (int off = 1; off < 64; off <<= 1) {
            int t = __shfl_up(s, off, 64);
            if (lane >= off) s += t;
        }
        if (lane == 63) wsum[wid] = s;
        __syncthreads();
        if (tid < 16) {
            int sc = wsum[tid];
#pragma unroll
            for (int off = 1; off < 16; off <<= 1) {
                int u = __shfl_up(sc, off, 16);
                if (tid >= off) sc += u;
            }
            wsum[tid] = sc;
        }
        __syncthreads();
        int prev = (wid > 0) ? wsum[wid - 1] : 0;
        int carry = carry_s;
        int incl = carry + prev + s;
        if (i < n) {
            int excl = incl - v;
            row_ptr[i] = excl;
            wptr[i]    = excl;
            ea_loop[i] = ea_sum[i] / fmaxf((float)v, 1.0f);
        }
        __syncthreads();
        if (tid == 0) carry_s = carry + wsum[15];
        __syncthreads();
    }
    if (tid == 0) row_ptr[n] = carry_s;
}

// ---------------------------------------------------------------------------
// Kernel 3: scatter edges into CSR order
// ---------------------------------------------------------------------------
__global__ void edge_scatter(const int* __restrict__ ei, const float* __restrict__ ea,
                             int* __restrict__ wptr, int* __restrict__ ssrc,
                             float* __restrict__ sea, int E) {
    int e = blockIdx.x * blockDim.x + threadIdx.x;
    if (e < E) {
        int d = ei[E + e];
        int pos = atomicAdd(&wptr[d], 1);
        ssrc[pos] = ei[e];
        sea[pos]  = ea[e];
    }
}

// ---------------------------------------------------------------------------
// Conversion kernels: fp32 -> bf16 (elementwise), fp32 [K][N] -> bf16 [N][K]
// ---------------------------------------------------------------------------
__global__ void cvt_bf16(const float* __restrict__ in, unsigned short* __restrict__ out, int sz) {
    int i = blockIdx.x * blockDim.x + threadIdx.x;
    if (i < sz) out[i] = f2bf(in[i]);
}
__global__ void tr_cvt_bf16(const float* __restrict__ in, unsigned short* __restrict__ out,
                            int K, int N) {
    int i = blockIdx.x * blockDim.x + threadIdx.x;
    if (i < K * N) {
        int k = i / N, nn = i - k * N;
        out[nn * K + k] = f2bf(in[i]);
    }
}

// ---------------------------------------------------------------------------
// Kernel 4: bf16 MFMA GEMM + bias (B pre-transposed), 64x64 tile, BK=32.
// ---------------------------------------------------------------------------
__global__ void __launch_bounds__(256)
gemm_bf16(const unsigned short* __restrict__ A, const unsigned short* __restrict__ Bt,
          const float* __restrict__ bias, unsigned short* __restrict__ C,
          int M, int N, int K) {
    __shared__ __attribute__((aligned(16))) unsigned short As[64 * 40];
    __shared__ __attribute__((aligned(16))) unsigned short Bs[64 * 40];
    int tid  = threadIdx.x;
    int wave = tid >> 6, lane = tid & 63;
    int m0 = blockIdx.x * 64, n0 = blockIdx.y * 64;
    int row = tid >> 2, kg = (tid & 3) * 8;

    f32x4 acc[4] = {};
    for (int kk = 0; kk < K; kk += 32) {
        int gm = m0 + row;
        uint4 av;
        if (gm < M) av = *(const uint4*)(A + (size_t)gm * K + kk + kg);
        else        av = make_uint4(0, 0, 0, 0);
        *(uint4*)&As[row * 40 + kg] = av;
        uint4 bv = *(const uint4*)(Bt + (size_t)(n0 + row) * K + kk + kg);
        *(uint4*)&Bs[row * 40 + kg] = bv;
        __syncthreads();
        short8 a = *(const short8*)&As[(wave * 16 + (lane & 15)) * 40 + (lane >> 4) * 8];
#pragma unroll
        for (int g = 0; g < 4; ++g) {
            short8 b = *(const short8*)&Bs[(g * 16 + (lane & 15)) * 40 + (lane >> 4) * 8];
            acc[g] = __builtin_amdgcn_mfma_f32_16x16x32_bf16(a, b, acc[g], 0, 0, 0);
        }
        __syncthreads();
    }
#pragma unroll
    for (int g = 0; g < 4; ++g) {
        int col = n0 + g * 16 + (lane & 15);
        float bs = bias[col];
#pragma unroll
        for (int r = 0; r < 4; ++r) {
            int grow = m0 + wave * 16 + (lane >> 4) * 4 + r;
            if (grow < M) C[(size_t)grow * N + col] = f2bf(acc[g][r] + bs);
        }
    }
}

// ---------------------------------------------------------------------------
// helpers for gat_agg
// ---------------------------------------------------------------------------
template <int NV>
__device__ __forceinline__ void ld_row(float* r, const float* p) {
    if constexpr (NV == 4) {
        float4 t = *(const float4*)p;
        r[0] = t.x; r[1] = t.y; r[2] = t.z; r[3] = t.w;
    } else {
        float2 t = *(const float2*)p;
        r[0] = t.x; r[1] = t.y;
    }
}
// gather NV bf16 from (uniform base) + per-lane offset
template <int NV>
__device__ __forceinline__ uint2 ld_bf(const unsigned short* __restrict__ base, int laneoff) {
    uint2 r;
    if constexpr (NV == 4) r = *(const uint2*)(base + laneoff);
    else { r.x = *(const unsigned int*)(base + laneoff); r.y = 0; }
    return r;
}
// reduction of vs over the C-channel group (G lanes)
template <int G>
__device__ __forceinline__ float grp_reduce(float vs) {
    vs = dpp_add<0xB1>(vs);              // xor 1 (quad_perm [1,0,3,2])
    vs = dpp_add<0x4E>(vs);              // xor 2 (quad_perm [2,3,0,1])
    vs = dpp_add<0x141>(vs);             // xor 4 (row_half_mirror)
    if constexpr (G >= 16) vs = dpp_add<0x140>(vs);   // xor 8 (row_mirror)
    if constexpr (G >= 32) {             // xor 16 within 32-lane group
        int t = __builtin_amdgcn_ds_swizzle(__float_as_int(vs), 0x401F);
        vs += __int_as_float(t);
    }
    if constexpr (G >= 64) vs += __shfl_xor(vs, 32, 64);
    return vs;
}

// ---------------------------------------------------------------------------
// Kernel 5: fused GATv2 gather(bf16) + score + softmax + aggregate + relu.
// One wave per dst node.  Edge (src,w) pairs are batch-loaded 64 at a time
// into lanes and extracted per edge via v_readlane -> SGPR, so the xl-row
// gather uses an SGPR base + hoisted lane offset (zero per-edge VALU addr
// math).  Score reduction is DPP-based.  Self-loop peeled out of the loop.
// ---------------------------------------------------------------------------
template <int HC, int C, bool OUT_BF16>
__global__ void __launch_bounds__(256)
gat_agg(const unsigned short* __restrict__ xl, const unsigned short* __restrict__ xr,
        const float* __restrict__ We, const float* __restrict__ att,
        const float* __restrict__ bias,
        const int* __restrict__ row_ptr, const int* __restrict__ ssrc,
        const float* __restrict__ sea, const float* __restrict__ ea_loop,
        void* __restrict__ out, int n) {
    constexpr int NV = HC / 64;
    constexpr int G  = C / NV;
    int wave = threadIdx.x >> 6;
    int lane = threadIdx.x & 63;
    int node = blockIdx.x * 4 + wave;
    if (node >= n) return;
    int laneoff = lane * NV;

    float xr_r[NV], We_r[NV], att_r[NV], o[NV];
    {
        uint2 u = ld_bf<NV>(xr + (size_t)node * HC, laneoff);
        if constexpr (NV == 4) { bf2f(u.x, xr_r[0], xr_r[1]); bf2f(u.y, xr_r[2], xr_r[3]); }
        else                   { bf2f(u.x, xr_r[0], xr_r[1]); }
    }
    ld_row<NV>(We_r, We + laneoff);
    ld_row<NV>(att_r, att + laneoff);

    int start = __builtin_amdgcn_readfirstlane(row_ptr[node]);
    int end   = __builtin_amdgcn_readfirstlane(row_ptr[node + 1]);
    float ea_l = ea_loop[node];
    float l = 0.0f;

    // ---- self-loop edge (src = node, w = ea_loop) ----
    {
        uint2 u = ld_bf<NV>(xl + (size_t)node * HC, laneoff);
        float xf[NV];
        if constexpr (NV == 4) { bf2f(u.x, xf[0], xf[1]); bf2f(u.y, xf[2], xf[3]); }
        else                   { bf2f(u.x, xf[0], xf[1]); }
        float vs = 0.0f;
#pragma unroll
        for (int j = 0; j < NV; ++j) {
            float t  = fmaf(ea_l, We_r[j], xr_r[j]);
            float mm = xf[j] + t;
            float lr = fmaxf(mm, 0.0f) + NEG_SLOPE * fminf(mm, 0.0f);
            vs = fmaf(lr, att_r[j], vs);
        }
        vs = grp_reduce<G>(vs);
        float pr = __expf(vs);
        l = pr;
#pragma unroll
        for (int j = 0; j < NV; ++j) o[j] = pr * xf[j];
    }

    // ---- real edges, batches of 64 ----
    int cnt = end - start;
    for (int b = 0; b < cnt; b += 64) {
        int rem = cnt - b;
        if (rem > 64) rem = 64;
        int idx = start + b + lane;
        int idxc = (idx < end) ? idx : (end - 1);
        int   srcv = ssrc[idxc];
        float wvv  = sea[idxc];

        int   s_src = __builtin_amdgcn_readlane(srcv, 0);
        float s_w   = __int_as_float(__builtin_amdgcn_readlane(__float_as_int(wvv), 0));
        uint2 cur = ld_bf<NV>(xl + (size_t)s_src * HC, laneoff);

        for (int j = 0; j < rem; ++j) {
            int jn = (j + 1 < rem) ? (j + 1) : j;
            int   n_src = __builtin_amdgcn_readlane(srcv, jn);
            float n_w   = __int_as_float(__builtin_amdgcn_readlane(__float_as_int(wvv), jn));
            uint2 nxt = ld_bf<NV>(xl + (size_t)n_src * HC, laneoff);

            float xf[NV];
            if constexpr (NV == 4) { bf2f(cur.x, xf[0], xf[1]); bf2f(cur.y, xf[2], xf[3]); }
            else                   { bf2f(cur.x, xf[0], xf[1]); }
            float vs = 0.0f;
#pragma unroll
            for (int j2 = 0; j2 < NV; ++j2) {
                float t  = fmaf(s_w, We_r[j2], xr_r[j2]);
                float mm = xf[j2] + t;
                float lr = fmaxf(mm, 0.0f) + NEG_SLOPE * fminf(mm, 0.0f);
                vs = fmaf(lr, att_r[j2], vs);
            }
            vs = grp_reduce<G>(vs);
            float pr = __expf(vs);
            l += pr;
#pragma unroll
            for (int j2 = 0; j2 < NV; ++j2) o[j2] = fmaf(pr, xf[j2], o[j2]);

            cur = nxt; s_w = n_w;
        }
    }

    float inv = 1.0f / (l + 1e-16f);
    float b_r[NV];
    ld_row<NV>(b_r, bias + laneoff);
    float v[NV];
#pragma unroll
    for (int j = 0; j < NV; ++j) v[j] = fmaxf(o[j] * inv + b_r[j], 0.0f);

    if constexpr (OUT_BF16) {
        unsigned short* op = (unsigned short*)out + (size_t)node * HC + laneoff;
        if constexpr (NV == 4) {
            uint2 t;
            t.x = (unsigned int)f2bf(v[0]) | ((unsigned int)f2bf(v[1]) << 16);
            t.y = (unsigned int)f2bf(v[2]) | ((unsigned int)f2bf(v[3]) << 16);
            *(uint2*)op = t;
        } else {
            *(unsigned int*)op = (unsigned int)f2bf(v[0]) | ((unsigned int)f2bf(v[1]) << 16);
        }
    } else {
        float* op = (float*)out + (size_t)node * HC + laneoff;
        if constexpr (NV == 4) { *(float4*)op = make_float4(v[0], v[1], v[2], v[3]); }
        else                   { *(float2*)op = make_float2(v[0], v[1]); }
    }
}

// ---------------------------------------------------------------------------
// Kernel 6: column partial sums of h2 [n,128] -> partial[gridDim.x*128]
// ---------------------------------------------------------------------------
__global__ void pool_partial(const float* __restrict__ h2, float* __restrict__ partial, int n) {
    int t = threadIdx.x;
    float s = 0.0f;
    for (int r = blockIdx.x; r < n; r += gridDim.x) s += h2[(size_t)r * 128 + t];
    partial[blockIdx.x * 128 + t] = s;
}

// ---------------------------------------------------------------------------
// Kernel 7: finish pooling, softmax over 128, sigmoid(alpha). 1 block x 128.
// ---------------------------------------------------------------------------
__global__ void pool_final(const float* __restrict__ partial, int nb,
                           const float* __restrict__ alpha_in,
                           float* __restrict__ out, int n) {
    __shared__ float red[4];
    int t = threadIdx.x;
    float s = 0.0f;
    for (int b = 0; b < nb; ++b) s += partial[b * 128 + t];
    float mean = s / (float)n;
    float mx = mean;
#pragma unroll
    for (int off = 32; off > 0; off >>= 1) mx = fmaxf(mx, __shfl_xor(mx, off, 64));
    if ((t & 63) == 0) red[t >> 6] = mx;
    __syncthreads();
    mx = fmaxf(red[0], red[1]);
    float ex = __expf(mean - mx);
    float sm = ex;
#pragma unroll
    for (int off = 32; off > 0; off >>= 1) sm += __shfl_xor(sm, off, 64);
    if ((t & 63) == 0) red[2 + (t >> 6)] = sm;
    __syncthreads();
    sm = red[2] + red[3];
    out[t] = ex / sm;
    if (t == 0) out[128] = 1.0f / (1.0f + __expf(-alpha_in[0]));
}

// ---------------------------------------------------------------------------
extern "C" void kernel_launch(void* const* d_in, const int* in_sizes, int n_in,
                              void* d_out, int out_size, void* d_ws, size_t ws_size,
                              hipStream_t stream) {
    const float* x    = (const float*)d_in[0];
    const int*   ei   = (const int*)d_in[1];
    const float* ea   = (const float*)d_in[2];
    const float* W1l  = (const float*)d_in[3];
    const float* b1l  = (const float*)d_in[4];
    const float* W1r  = (const float*)d_in[5];
    const float* b1r  = (const float*)d_in[6];
    const float* We1  = (const float*)d_in[7];
    const float* att1 = (const float*)d_in[8];
    const float* bias1= (const float*)d_in[9];
    const float* W2l  = (const float*)d_in[10];
    const float* b2l  = (const float*)d_in[11];
    const float* W2r  = (const float*)d_in[12];
    const float* b2r  = (const float*)d_in[13];
    const float* We2  = (const float*)d_in[14];
    const float* att2 = (const float*)d_in[15];
    const float* bias2= (const float*)d_in[16];
    const float* alpha= (const float*)d_in[17];
    float* out = (float*)d_out;

    const int F = 128, HC1 = 256, HC2 = 128;
    const int n = in_sizes[0] / F;       // 20000
    const int E = in_sizes[1] / 2;       // 640000

    char* ws = (char*)d_ws;
    size_t off = 0;
    auto alloc = [&](size_t bytes) { size_t p = off; off += (bytes + 255) & ~(size_t)255; return p; };

    int*   deg     = (int*)  (ws + alloc((size_t)n * 4));
    float* ea_sum  = (float*)(ws + alloc((size_t)n * 4));
    int*   row_ptr = (int*)  (ws + alloc((size_t)(n + 1) * 4));
    int*   wptr    = (int*)  (ws + alloc((size_t)n * 4));
    float* ea_loop = (float*)(ws + alloc((size_t)n * 4));
    int*   ssrc    = (int*)  (ws + alloc((size_t)E * 4));
    float* sea     = (float*)(ws + alloc((size_t)E * 4));
    unsigned short* xb    = (unsigned short*)(ws + alloc((size_t)n * F * 2));
    unsigned short* W1lt  = (unsigned short*)(ws + alloc((size_t)F * HC1 * 2));
    unsigned short* W1rt  = (unsigned short*)(ws + alloc((size_t)F * HC1 * 2));
    unsigned short* W2lt  = (unsigned short*)(ws + alloc((size_t)HC1 * HC2 * 2));
    unsigned short* W2rt  = (unsigned short*)(ws + alloc((size_t)HC1 * HC2 * 2));
    unsigned short* xl1   = (unsigned short*)(ws + alloc((size_t)n * HC1 * 2));
    unsigned short* xr1   = (unsigned short*)(ws + alloc((size_t)n * HC1 * 2));
    unsigned short* h1    = (unsigned short*)(ws + alloc((size_t)n * HC1 * 2));
    float* h2      = (float*)(ws + alloc((size_t)n * HC2 * 4));
    float* partial = (float*)(ws + alloc((size_t)256 * 128 * 4));
    unsigned short* xl2 = xl1;
    unsigned short* xr2 = xr1;
    const int NB_POOL = 256;

    (void)hipMemsetAsync(deg, 0, (size_t)n * 4, stream);
    (void)hipMemsetAsync(ea_sum, 0, (size_t)n * 4, stream);

    int tb = 256;
    edge_hist<<<(E + tb - 1) / tb, tb, 0, stream>>>(ei, ea, deg, ea_sum, E);
    scan_deg<<<1, 1024, 0, stream>>>(deg, ea_sum, row_ptr, wptr, ea_loop, n);
    edge_scatter<<<(E + tb - 1) / tb, tb, 0, stream>>>(ei, ea, wptr, ssrc, sea, E);

    cvt_bf16<<<(n * F + tb - 1) / tb, tb, 0, stream>>>(x, xb, n * F);
    tr_cvt_bf16<<<(F * HC1 + tb - 1) / tb, tb, 0, stream>>>(W1l, W1lt, F, HC1);
    tr_cvt_bf16<<<(F * HC1 + tb - 1) / tb, tb, 0, stream>>>(W1r, W1rt, F, HC1);
    tr_cvt_bf16<<<(HC1 * HC2 + tb - 1) / tb, tb, 0, stream>>>(W2l, W2lt, HC1, HC2);
    tr_cvt_bf16<<<(HC1 * HC2 + tb - 1) / tb, tb, 0, stream>>>(W2r, W2rt, HC1, HC2);

    {
        dim3 grid((n + 63) / 64, HC1 / 64);
        gemm_bf16<<<grid, 256, 0, stream>>>(xb, W1lt, b1l, xl1, n, HC1, F);
        gemm_bf16<<<grid, 256, 0, stream>>>(xb, W1rt, b1r, xr1, n, HC1, F);
    }
    gat_agg<256, 32, true><<<(n + 3) / 4, 256, 0, stream>>>(xl1, xr1, We1, att1, bias1,
                                                            row_ptr, ssrc, sea, ea_loop, h1, n);
    {
        dim3 grid((n + 63) / 64, HC2 / 64);
        gemm_bf16<<<grid, 256, 0, stream>>>(h1, W2lt, b2l, xl2, n, HC2, HC1);
        gemm_bf16<<<grid, 256, 0, stream>>>(h1, W2rt, b2r, xr2, n, HC2, HC1);
    }
    gat_agg<128, 128, false><<<(n + 3) / 4, 256, 0, stream>>>(xl2, xr2, We2, att2, bias2,
                                                              row_ptr, ssrc, sea, ea_loop, h2, n);

    pool_partial<<<NB_POOL, 128, 0, stream>>>(h2, partial, n);
    pool_final<<<1, 128, 0, stream>>>(partial, NB_POOL, alpha, out, n);
}

// Round 6
// 409.042 us; speedup vs baseline: 1.6791x; 1.1488x over previous
//
#include <hip/hip_runtime.h>
#include <math.h>

#define NEG_SLOPE 0.2f

typedef __attribute__((ext_vector_type(8))) short short8;   // 8 bf16 (4 VGPRs)
typedef __attribute__((ext_vector_type(4))) float f32x4;

__device__ __forceinline__ unsigned short f2bf(float f) {
    unsigned int u = __float_as_uint(f);
    unsigned int r = (u + 0x7fffu + ((u >> 16) & 1u)) >> 16;   // RNE
    return (unsigned short)r;
}
__device__ __forceinline__ void bf2f(unsigned int u, float& a, float& b) {
    a = __uint_as_float(u << 16);
    b = __uint_as_float(u & 0xffff0000u);
}
template <int CTRL>
__device__ __forceinline__ float dpp_add(float v) {
    int t = __builtin_amdgcn_update_dpp(0, __float_as_int(v), CTRL, 0xF, 0xF, true);
    return v + __int_as_float(t);
}

// ---------------------------------------------------------------------------
// Kernel 1: per-edge histogram: deg[dst]++, ea_sum[dst] += edge_attr[e]
// ---------------------------------------------------------------------------
__global__ void edge_hist(const int* __restrict__ ei, const float* __restrict__ ea,
                          int* __restrict__ deg, float* __restrict__ ea_sum, int E) {
    int e = blockIdx.x * blockDim.x + threadIdx.x;
    if (e < E) {
        int d = ei[E + e];
        atomicAdd(&deg[d], 1);
        atomicAdd(&ea_sum[d], ea[e]);
    }
}

// ---------------------------------------------------------------------------
// Kernel 2: single-block scan of deg -> row_ptr, ea_loop = ea_sum/max(deg,1)
// ---------------------------------------------------------------------------
__global__ void scan_deg(const int* __restrict__ deg, const float* __restrict__ ea_sum,
                         int* __restrict__ row_ptr, int* __restrict__ wptr,
                         float* __restrict__ ea_loop, int n) {
    __shared__ int wsum[16];
    __shared__ int carry_s;
    int tid = threadIdx.x;
    int wid = tid >> 6, lane = tid & 63;
    if (tid == 0) carry_s = 0;
    __syncthreads();
    for (int base = 0; base < n; base += 1024) {
        int i = base + tid;
        int v = (i < n) ? deg[i] : 0;
        int s = v;
#pragma unroll
        for (int off = 1; off < 64; off <<= 1) {
            int t = __shfl_up(s, off, 64);
            if (lane >= off) s += t;
        }
        if (lane == 63) wsum[wid] = s;
        __syncthreads();
        if (tid < 16) {
            int sc = wsum[tid];
#pragma unroll
            for (int off = 1; off < 16; off <<= 1) {
                int u = __shfl_up(sc, off, 16);
                if (tid >= off) sc += u;
            }
            wsum[tid] = sc;
        }
        __syncthreads();
        int prev = (wid > 0) ? wsum[wid - 1] : 0;
        int carry = carry_s;
        int incl = carry + prev + s;
        if (i < n) {
            int excl = incl - v;
            row_ptr[i] = excl;
            wptr[i]    = excl;
            ea_loop[i] = ea_sum[i] / fmaxf((float)v, 1.0f);
        }
        __syncthreads();
        if (tid == 0) carry_s = carry + wsum[15];
        __syncthreads();
    }
    if (tid == 0) row_ptr[n] = carry_s;
}

// ---------------------------------------------------------------------------
// Kernel 3: scatter edges into CSR order
// ---------------------------------------------------------------------------
__global__ void edge_scatter(const int* __restrict__ ei, const float* __restrict__ ea,
                             int* __restrict__ wptr, int* __restrict__ ssrc,
                             float* __restrict__ sea, int E) {
    int e = blockIdx.x * blockDim.x + threadIdx.x;
    if (e < E) {
        int d = ei[E + e];
        int pos = atomicAdd(&wptr[d], 1);
        ssrc[pos] = ei[e];
        sea[pos]  = ea[e];
    }
}

// ---------------------------------------------------------------------------
// Conversion kernels: fp32 -> bf16 (elementwise), fp32 [K][N] -> bf16 [N][K]
// ---------------------------------------------------------------------------
__global__ void cvt_bf16(const float* __restrict__ in, unsigned short* __restrict__ out, int sz) {
    int i = blockIdx.x * blockDim.x + threadIdx.x;
    if (i < sz) out[i] = f2bf(in[i]);
}
__global__ void tr_cvt_bf16(const float* __restrict__ in, unsigned short* __restrict__ out,
                            int K, int N) {
    int i = blockIdx.x * blockDim.x + threadIdx.x;
    if (i < K * N) {
        int k = i / N, nn = i - k * N;
        out[nn * K + k] = f2bf(in[i]);
    }
}

// ---------------------------------------------------------------------------
// Kernel 4: bf16 MFMA GEMM + bias (B pre-transposed), 64x64 tile, BK=32.
// ---------------------------------------------------------------------------
__global__ void __launch_bounds__(256)
gemm_bf16(const unsigned short* __restrict__ A, const unsigned short* __restrict__ Bt,
          const float* __restrict__ bias, unsigned short* __restrict__ C,
          int M, int N, int K) {
    __shared__ __attribute__((aligned(16))) unsigned short As[64 * 40];
    __shared__ __attribute__((aligned(16))) unsigned short Bs[64 * 40];
    int tid  = threadIdx.x;
    int wave = tid >> 6, lane = tid & 63;
    int m0 = blockIdx.x * 64, n0 = blockIdx.y * 64;
    int row = tid >> 2, kg = (tid & 3) * 8;

    f32x4 acc[4] = {};
    for (int kk = 0; kk < K; kk += 32) {
        int gm = m0 + row;
        uint4 av;
        if (gm < M) av = *(const uint4*)(A + (size_t)gm * K + kk + kg);
        else        av = make_uint4(0, 0, 0, 0);
        *(uint4*)&As[row * 40 + kg] = av;
        uint4 bv = *(const uint4*)(Bt + (size_t)(n0 + row) * K + kk + kg);
        *(uint4*)&Bs[row * 40 + kg] = bv;
        __syncthreads();
        short8 a = *(const short8*)&As[(wave * 16 + (lane & 15)) * 40 + (lane >> 4) * 8];
#pragma unroll
        for (int g = 0; g < 4; ++g) {
            short8 b = *(const short8*)&Bs[(g * 16 + (lane & 15)) * 40 + (lane >> 4) * 8];
            acc[g] = __builtin_amdgcn_mfma_f32_16x16x32_bf16(a, b, acc[g], 0, 0, 0);
        }
        __syncthreads();
    }
#pragma unroll
    for (int g = 0; g < 4; ++g) {
        int col = n0 + g * 16 + (lane & 15);
        float bs = bias[col];
#pragma unroll
        for (int r = 0; r < 4; ++r) {
            int grow = m0 + wave * 16 + (lane >> 4) * 4 + r;
            if (grow < M) C[(size_t)grow * N + col] = f2bf(acc[g][r] + bs);
        }
    }
}

// ---------------------------------------------------------------------------
// helpers for gat_agg
// ---------------------------------------------------------------------------
template <int NV>
__device__ __forceinline__ void ld_row(float* r, const float* p) {
    if constexpr (NV == 4) {
        float4 t = *(const float4*)p;
        r[0] = t.x; r[1] = t.y; r[2] = t.z; r[3] = t.w;
    } else {
        float2 t = *(const float2*)p;
        r[0] = t.x; r[1] = t.y;
    }
}
template <int NV>
__device__ __forceinline__ uint2 ld_bf(const unsigned short* __restrict__ base, int laneoff) {
    uint2 r;
    if constexpr (NV == 4) r = *(const uint2*)(base + laneoff);
    else { r.x = *(const unsigned int*)(base + laneoff); r.y = 0; }
    return r;
}
template <int G>
__device__ __forceinline__ float grp_reduce(float vs) {
    vs = dpp_add<0xB1>(vs);              // xor 1
    vs = dpp_add<0x4E>(vs);              // xor 2
    vs = dpp_add<0x141>(vs);             // xor 4 (row_half_mirror)
    if constexpr (G >= 16) vs = dpp_add<0x140>(vs);   // xor 8 (row_mirror)
    if constexpr (G >= 32) {             // xor 16
        int t = __builtin_amdgcn_ds_swizzle(__float_as_int(vs), 0x401F);
        vs += __int_as_float(t);
    }
    if constexpr (G >= 64) vs += __shfl_xor(vs, 32, 64);
    return vs;
}

// ---------------------------------------------------------------------------
// Kernel 5: fused GATv2 gather(bf16) + score + softmax + aggregate + relu.
// One wave per dst node; edges batch-loaded 64/vec-load, extracted via
// v_readlane (SGPR base gathers); DPP score reduction; depth-2 gather pipeline.
// ---------------------------------------------------------------------------
template <int HC, int C, bool OUT_BF16>
__global__ void __launch_bounds__(256)
gat_agg(const unsigned short* __restrict__ xl, const unsigned short* __restrict__ xr,
        const float* __restrict__ We, const float* __restrict__ att,
        const float* __restrict__ bias,
        const int* __restrict__ row_ptr, const int* __restrict__ ssrc,
        const float* __restrict__ sea, const float* __restrict__ ea_loop,
        void* __restrict__ out, int n) {
    constexpr int NV = HC / 64;
    constexpr int G  = C / NV;
    int wave = threadIdx.x >> 6;
    int lane = threadIdx.x & 63;
    int node = blockIdx.x * 4 + wave;
    if (node >= n) return;
    int laneoff = lane * NV;

    float xr_r[NV], We_r[NV], att_r[NV], o[NV];
    {
        uint2 u = ld_bf<NV>(xr + (size_t)node * HC, laneoff);
        if constexpr (NV == 4) { bf2f(u.x, xr_r[0], xr_r[1]); bf2f(u.y, xr_r[2], xr_r[3]); }
        else                   { bf2f(u.x, xr_r[0], xr_r[1]); }
    }
    ld_row<NV>(We_r, We + laneoff);
    ld_row<NV>(att_r, att + laneoff);

    int start = __builtin_amdgcn_readfirstlane(row_ptr[node]);
    int end   = __builtin_amdgcn_readfirstlane(row_ptr[node + 1]);
    float ea_l = ea_loop[node];
    float l = 0.0f;

    // ---- self-loop edge ----
    {
        uint2 u = ld_bf<NV>(xl + (size_t)node * HC, laneoff);
        float xf[NV];
        if constexpr (NV == 4) { bf2f(u.x, xf[0], xf[1]); bf2f(u.y, xf[2], xf[3]); }
        else                   { bf2f(u.x, xf[0], xf[1]); }
        float vs = 0.0f;
#pragma unroll
        for (int j = 0; j < NV; ++j) {
            float t  = fmaf(ea_l, We_r[j], xr_r[j]);
            float mm = xf[j] + t;
            float lr = fmaxf(mm, 0.0f) + NEG_SLOPE * fminf(mm, 0.0f);
            vs = fmaf(lr, att_r[j], vs);
        }
        vs = grp_reduce<G>(vs);
        float pr = __expf(vs);
        l = pr;
#pragma unroll
        for (int j = 0; j < NV; ++j) o[j] = pr * xf[j];
    }

    // ---- real edges, batches of 64, depth-2 gather pipeline ----
    int cnt = end - start;
    for (int b = 0; b < cnt; b += 64) {
        int rem = cnt - b;
        if (rem > 64) rem = 64;
        int idx = start + b + lane;
        int idxc = (idx < end) ? idx : (end - 1);
        int   srcv = ssrc[idxc];
        float wvv  = sea[idxc];

        int s0 = __builtin_amdgcn_readlane(srcv, 0);
        uint2 cur = ld_bf<NV>(xl + (size_t)s0 * HC, laneoff);
        float wcur = __int_as_float(__builtin_amdgcn_readlane(__float_as_int(wvv), 0));
        uint2 nxt = cur; float wnxt = wcur;
        if (rem > 1) {
            int s1 = __builtin_amdgcn_readlane(srcv, 1);
            nxt  = ld_bf<NV>(xl + (size_t)s1 * HC, laneoff);
            wnxt = __int_as_float(__builtin_amdgcn_readlane(__float_as_int(wvv), 1));
        }

        for (int j = 0; j < rem; ++j) {
            uint2 n2 = nxt; float wn2 = wnxt;
            if (j + 2 < rem) {
                int s2 = __builtin_amdgcn_readlane(srcv, j + 2);
                n2  = ld_bf<NV>(xl + (size_t)s2 * HC, laneoff);
                wn2 = __int_as_float(__builtin_amdgcn_readlane(__float_as_int(wvv), j + 2));
            }

            float xf[NV];
            if constexpr (NV == 4) { bf2f(cur.x, xf[0], xf[1]); bf2f(cur.y, xf[2], xf[3]); }
            else                   { bf2f(cur.x, xf[0], xf[1]); }
            float vs = 0.0f;
#pragma unroll
            for (int j2 = 0; j2 < NV; ++j2) {
                float t  = fmaf(wcur, We_r[j2], xr_r[j2]);
                float mm = xf[j2] + t;
                float lr = fmaxf(mm, 0.0f) + NEG_SLOPE * fminf(mm, 0.0f);
                vs = fmaf(lr, att_r[j2], vs);
            }
            vs = grp_reduce<G>(vs);
            float pr = __expf(vs);
            l += pr;
#pragma unroll
            for (int j2 = 0; j2 < NV; ++j2) o[j2] = fmaf(pr, xf[j2], o[j2]);

            cur = nxt; wcur = wnxt;
            nxt = n2;  wnxt = wn2;
        }
    }

    float inv = 1.0f / (l + 1e-16f);
    float b_r[NV];
    ld_row<NV>(b_r, bias + laneoff);
    float v[NV];
#pragma unroll
    for (int j = 0; j < NV; ++j) v[j] = fmaxf(o[j] * inv + b_r[j], 0.0f);

    if constexpr (OUT_BF16) {
        unsigned short* op = (unsigned short*)out + (size_t)node * HC + laneoff;
        if constexpr (NV == 4) {
            uint2 t;
            t.x = (unsigned int)f2bf(v[0]) | ((unsigned int)f2bf(v[1]) << 16);
            t.y = (unsigned int)f2bf(v[2]) | ((unsigned int)f2bf(v[3]) << 16);
            *(uint2*)op = t;
        } else {
            *(unsigned int*)op = (unsigned int)f2bf(v[0]) | ((unsigned int)f2bf(v[1]) << 16);
        }
    } else {
        float* op = (float*)out + (size_t)node * HC + laneoff;
        if constexpr (NV == 4) { *(float4*)op = make_float4(v[0], v[1], v[2], v[3]); }
        else                   { *(float2*)op = make_float2(v[0], v[1]); }
    }
}

// ---------------------------------------------------------------------------
// Kernel 6: column partial sums of h2 [n,128] -> partial[gridDim.x*128]
// ---------------------------------------------------------------------------
__global__ void pool_partial(const float* __restrict__ h2, float* __restrict__ partial, int n) {
    int t = threadIdx.x;
    float s = 0.0f;
    for (int r = blockIdx.x; r < n; r += gridDim.x) s += h2[(size_t)r * 128 + t];
    partial[blockIdx.x * 128 + t] = s;
}

// ---------------------------------------------------------------------------
// Kernel 7: finish pooling, softmax over 128, sigmoid(alpha).
// 1024 threads (8 groups x 128 cols): each thread sums nb/8 strided partials
// (independent loads, deep MLP), LDS-reduce groups, then softmax.
// ---------------------------------------------------------------------------
__global__ void __launch_bounds__(1024)
pool_final(const float* __restrict__ partial, int nb,
           const float* __restrict__ alpha_in,
           float* __restrict__ out, int n) {
    __shared__ float acc[8][128];
    __shared__ float red[4];
    int t = threadIdx.x & 127;        // column
    int g = threadIdx.x >> 7;         // group 0..7
    float s = 0.0f;
    for (int b = g; b < nb; b += 8) s += partial[b * 128 + t];
    acc[g][t] = s;
    __syncthreads();
    if (threadIdx.x < 128) {
        float tot = 0.0f;
#pragma unroll
        for (int k = 0; k < 8; ++k) tot += acc[k][t];
        float mean = tot / (float)n;
        float mx = mean;
#pragma unroll
        for (int off = 32; off > 0; off >>= 1) mx = fmaxf(mx, __shfl_xor(mx, off, 64));
        if ((t & 63) == 0) red[t >> 6] = mx;
        __syncthreads();
        mx = fmaxf(red[0], red[1]);
        float ex = __expf(mean - mx);
        float sm = ex;
#pragma unroll
        for (int off = 32; off > 0; off >>= 1) sm += __shfl_xor(sm, off, 64);
        if ((t & 63) == 0) red[2 + (t >> 6)] = sm;
        __syncthreads();
        sm = red[2] + red[3];
        out[t] = ex / sm;
        if (t == 0) out[128] = 1.0f / (1.0f + __expf(-alpha_in[0]));
    }
}

// ---------------------------------------------------------------------------
extern "C" void kernel_launch(void* const* d_in, const int* in_sizes, int n_in,
                              void* d_out, int out_size, void* d_ws, size_t ws_size,
                              hipStream_t stream) {
    const float* x    = (const float*)d_in[0];
    const int*   ei   = (const int*)d_in[1];
    const float* ea   = (const float*)d_in[2];
    const float* W1l  = (const float*)d_in[3];
    const float* b1l  = (const float*)d_in[4];
    const float* W1r  = (const float*)d_in[5];
    const float* b1r  = (const float*)d_in[6];
    const float* We1  = (const float*)d_in[7];
    const float* att1 = (const float*)d_in[8];
    const float* bias1= (const float*)d_in[9];
    const float* W2l  = (const float*)d_in[10];
    const float* b2l  = (const float*)d_in[11];
    const float* W2r  = (const float*)d_in[12];
    const float* b2r  = (const float*)d_in[13];
    const float* We2  = (const float*)d_in[14];
    const float* att2 = (const float*)d_in[15];
    const float* bias2= (const float*)d_in[16];
    const float* alpha= (const float*)d_in[17];
    float* out = (float*)d_out;

    const int F = 128, HC1 = 256, HC2 = 128;
    const int n = in_sizes[0] / F;       // 20000
    const int E = in_sizes[1] / 2;       // 640000

    char* ws = (char*)d_ws;
    size_t off = 0;
    auto alloc = [&](size_t bytes) { size_t p = off; off += (bytes + 255) & ~(size_t)255; return p; };

    int*   deg     = (int*)  (ws + alloc((size_t)n * 4));
    float* ea_sum  = (float*)(ws + alloc((size_t)n * 4));
    int*   row_ptr = (int*)  (ws + alloc((size_t)(n + 1) * 4));
    int*   wptr    = (int*)  (ws + alloc((size_t)n * 4));
    float* ea_loop = (float*)(ws + alloc((size_t)n * 4));
    int*   ssrc    = (int*)  (ws + alloc((size_t)E * 4));
    float* sea     = (float*)(ws + alloc((size_t)E * 4));
    unsigned short* xb    = (unsigned short*)(ws + alloc((size_t)n * F * 2));
    unsigned short* W1lt  = (unsigned short*)(ws + alloc((size_t)F * HC1 * 2));
    unsigned short* W1rt  = (unsigned short*)(ws + alloc((size_t)F * HC1 * 2));
    unsigned short* W2lt  = (unsigned short*)(ws + alloc((size_t)HC1 * HC2 * 2));
    unsigned short* W2rt  = (unsigned short*)(ws + alloc((size_t)HC1 * HC2 * 2));
    unsigned short* xl1   = (unsigned short*)(ws + alloc((size_t)n * HC1 * 2));
    unsigned short* xr1   = (unsigned short*)(ws + alloc((size_t)n * HC1 * 2));
    unsigned short* h1    = (unsigned short*)(ws + alloc((size_t)n * HC1 * 2));
    float* h2      = (float*)(ws + alloc((size_t)n * HC2 * 4));
    float* partial = (float*)(ws + alloc((size_t)256 * 128 * 4));
    unsigned short* xl2 = xl1;
    unsigned short* xr2 = xr1;
    const int NB_POOL = 256;

    (void)hipMemsetAsync(deg, 0, (size_t)n * 4, stream);
    (void)hipMemsetAsync(ea_sum, 0, (size_t)n * 4, stream);

    int tb = 256;
    edge_hist<<<(E + tb - 1) / tb, tb, 0, stream>>>(ei, ea, deg, ea_sum, E);
    scan_deg<<<1, 1024, 0, stream>>>(deg, ea_sum, row_ptr, wptr, ea_loop, n);
    edge_scatter<<<(E + tb - 1) / tb, tb, 0, stream>>>(ei, ea, wptr, ssrc, sea, E);

    cvt_bf16<<<(n * F + tb - 1) / tb, tb, 0, stream>>>(x, xb, n * F);
    tr_cvt_bf16<<<(F * HC1 + tb - 1) / tb, tb, 0, stream>>>(W1l, W1lt, F, HC1);
    tr_cvt_bf16<<<(F * HC1 + tb - 1) / tb, tb, 0, stream>>>(W1r, W1rt, F, HC1);
    tr_cvt_bf16<<<(HC1 * HC2 + tb - 1) / tb, tb, 0, stream>>>(W2l, W2lt, HC1, HC2);
    tr_cvt_bf16<<<(HC1 * HC2 + tb - 1) / tb, tb, 0, stream>>>(W2r, W2rt, HC1, HC2);

    {
        dim3 grid((n + 63) / 64, HC1 / 64);
        gemm_bf16<<<grid, 256, 0, stream>>>(xb, W1lt, b1l, xl1, n, HC1, F);
        gemm_bf16<<<grid, 256, 0, stream>>>(xb, W1rt, b1r, xr1, n, HC1, F);
    }
    gat_agg<256, 32, true><<<(n + 3) / 4, 256, 0, stream>>>(xl1, xr1, We1, att1, bias1,
                                                            row_ptr, ssrc, sea, ea_loop, h1, n);
    {
        dim3 grid((n + 63) / 64, HC2 / 64);
        gemm_bf16<<<grid, 256, 0, stream>>>(h1, W2lt, b2l, xl2, n, HC2, HC1);
        gemm_bf16<<<grid, 256, 0, stream>>>(h1, W2rt, b2r, xr2, n, HC2, HC1);
    }
    gat_agg<128, 128, false><<<(n + 3) / 4, 256, 0, stream>>>(xl2, xr2, We2, att2, bias2,
                                                              row_ptr, ssrc, sea, ea_loop, h2, n);

    pool_partial<<<NB_POOL, 128, 0, stream>>>(h2, partial, n);
    pool_final<<<1, 1024, 0, stream>>>(partial, NB_POOL, alpha, out, n);
}

// Round 7
// 357.345 us; speedup vs baseline: 1.9221x; 1.1447x over previous
//
#include <hip/hip_runtime.h>
#include <math.h>

#define NEG_SLOPE 0.2f

typedef __attribute__((ext_vector_type(8))) short short8;   // 8 bf16 (4 VGPRs)
typedef __attribute__((ext_vector_type(4))) float f32x4;

__device__ __forceinline__ int imin(int a, int b) { return a < b ? a : b; }

__device__ __forceinline__ unsigned short f2bf(float f) {
    unsigned int u = __float_as_uint(f);
    unsigned int r = (u + 0x7fffu + ((u >> 16) & 1u)) >> 16;   // RNE
    return (unsigned short)r;
}
__device__ __forceinline__ void bf2f(unsigned int u, float& a, float& b) {
    a = __uint_as_float(u << 16);
    b = __uint_as_float(u & 0xffff0000u);
}
template <int CTRL>
__device__ __forceinline__ float dpp_add(float v) {
    int t = __builtin_amdgcn_update_dpp(0, __float_as_int(v), CTRL, 0xF, 0xF, true);
    return v + __int_as_float(t);
}

// ---------------------------------------------------------------------------
// Kernel 1: per-edge histogram: deg[dst]++, ea_sum[dst] += edge_attr[e]
// ---------------------------------------------------------------------------
__global__ void edge_hist(const int* __restrict__ ei, const float* __restrict__ ea,
                          int* __restrict__ deg, float* __restrict__ ea_sum, int E) {
    int e = blockIdx.x * blockDim.x + threadIdx.x;
    if (e < E) {
        int d = ei[E + e];
        atomicAdd(&deg[d], 1);
        atomicAdd(&ea_sum[d], ea[e]);
    }
}

// ---------------------------------------------------------------------------
// 3-phase parallel scan of deg (chunk = 1024 per block).
// scan_a: block totals.  scan_b: 1-wave exclusive scan of block totals (+ total
// to row_ptr[n]).  scan_c: block-local scan + offset, writes row_ptr/wptr/ea_loop.
// ---------------------------------------------------------------------------
__global__ void scan_a(const int* __restrict__ deg, int* __restrict__ bsum, int n) {
    __shared__ int wred[4];
    int base = blockIdx.x * 1024;
    int tid = threadIdx.x;
    int s = 0;
#pragma unroll
    for (int k = 0; k < 4; ++k) {
        int i = base + tid + k * 256;
        if (i < n) s += deg[i];
    }
#pragma unroll
    for (int off = 32; off > 0; off >>= 1) s += __shfl_xor(s, off, 64);
    if ((tid & 63) == 0) wred[tid >> 6] = s;
    __syncthreads();
    if (tid == 0) bsum[blockIdx.x] = wred[0] + wred[1] + wred[2] + wred[3];
}

__global__ void scan_b(int* __restrict__ bsum, int* __restrict__ row_ptr, int B, int n) {
    int tid = threadIdx.x;           // 64 threads, B <= 64
    int v = (tid < B) ? bsum[tid] : 0;
    int s = v;
#pragma unroll
    for (int off = 1; off < 64; off <<= 1) {
        int t = __shfl_up(s, off, 64);
        if (tid >= off) s += t;
    }
    if (tid < B) bsum[tid] = s - v;  // exclusive
    if (tid == 63) row_ptr[n] = s;   // total
}

__global__ void scan_c(const int* __restrict__ deg, const float* __restrict__ ea_sum,
                       const int* __restrict__ bsum, int* __restrict__ row_ptr,
                       int* __restrict__ wptr, float* __restrict__ ea_loop, int n) {
    __shared__ int wtot[4];
    int tid = threadIdx.x;
    int wid = tid >> 6, lane = tid & 63;
    int i0 = blockIdx.x * 1024 + tid * 4;
    int4 v = make_int4(0, 0, 0, 0);
    float4 es = make_float4(0, 0, 0, 0);
    if (i0 < n) { v = *(const int4*)(deg + i0); es = *(const float4*)(ea_sum + i0); }
    int tsum = v.x + v.y + v.z + v.w;
    int s = tsum;
#pragma unroll
    for (int off = 1; off < 64; off <<= 1) {
        int t = __shfl_up(s, off, 64);
        if (lane >= off) s += t;
    }
    if (lane == 63) wtot[wid] = s;
    __syncthreads();
    int wpre = 0;
#pragma unroll
    for (int k = 0; k < 4; ++k) if (k < wid) wpre += wtot[k];
    int pre = bsum[blockIdx.x] + wpre + (s - tsum);
    if (i0 < n) {
        int4 e;
        e.x = pre;
        e.y = pre + v.x;
        e.z = e.y + v.y;
        e.w = e.z + v.z;
        *(int4*)(row_ptr + i0) = e;
        *(int4*)(wptr + i0) = e;
        float4 el;
        el.x = es.x / fmaxf((float)v.x, 1.0f);
        el.y = es.y / fmaxf((float)v.y, 1.0f);
        el.z = es.z / fmaxf((float)v.z, 1.0f);
        el.w = es.w / fmaxf((float)v.w, 1.0f);
        *(float4*)(ea_loop + i0) = el;
    }
}

// ---------------------------------------------------------------------------
// Kernel 3: scatter edges into CSR order
// ---------------------------------------------------------------------------
__global__ void edge_scatter(const int* __restrict__ ei, const float* __restrict__ ea,
                             int* __restrict__ wptr, int* __restrict__ ssrc,
                             float* __restrict__ sea, int E) {
    int e = blockIdx.x * blockDim.x + threadIdx.x;
    if (e < E) {
        int d = ei[E + e];
        int pos = atomicAdd(&wptr[d], 1);
        ssrc[pos] = ei[e];
        sea[pos]  = ea[e];
    }
}

// ---------------------------------------------------------------------------
// Conversion kernels
// ---------------------------------------------------------------------------
__global__ void cvt_bf16(const float* __restrict__ in, unsigned short* __restrict__ out, int sz) {
    int i = blockIdx.x * blockDim.x + threadIdx.x;
    if (i < sz) out[i] = f2bf(in[i]);
}
__global__ void tr_cvt_bf16(const float* __restrict__ in, unsigned short* __restrict__ out,
                            int K, int N) {
    int i = blockIdx.x * blockDim.x + threadIdx.x;
    if (i < K * N) {
        int k = i / N, nn = i - k * N;
        out[nn * K + k] = f2bf(in[i]);
    }
}
__global__ void bias_cat(const float* __restrict__ a, const float* __restrict__ b,
                         float* __restrict__ out, int na, int ntot) {
    int i = blockIdx.x * blockDim.x + threadIdx.x;
    if (i < ntot) out[i] = (i < na) ? a[i] : b[i - na];
}

// ---------------------------------------------------------------------------
// Kernel 4: bf16 MFMA GEMM + bias (B pre-transposed), 64x64 tile, BK=32.
// ---------------------------------------------------------------------------
__global__ void __launch_bounds__(256)
gemm_bf16(const unsigned short* __restrict__ A, const unsigned short* __restrict__ Bt,
          const float* __restrict__ bias, unsigned short* __restrict__ C,
          int M, int N, int K) {
    __shared__ __attribute__((aligned(16))) unsigned short As[64 * 40];
    __shared__ __attribute__((aligned(16))) unsigned short Bs[64 * 40];
    int tid  = threadIdx.x;
    int wave = tid >> 6, lane = tid & 63;
    int m0 = blockIdx.x * 64, n0 = blockIdx.y * 64;
    int row = tid >> 2, kg = (tid & 3) * 8;

    f32x4 acc[4] = {};
    for (int kk = 0; kk < K; kk += 32) {
        int gm = m0 + row;
        uint4 av;
        if (gm < M) av = *(const uint4*)(A + (size_t)gm * K + kk + kg);
        else        av = make_uint4(0, 0, 0, 0);
        *(uint4*)&As[row * 40 + kg] = av;
        uint4 bv = *(const uint4*)(Bt + (size_t)(n0 + row) * K + kk + kg);
        *(uint4*)&Bs[row * 40 + kg] = bv;
        __syncthreads();
        short8 a = *(const short8*)&As[(wave * 16 + (lane & 15)) * 40 + (lane >> 4) * 8];
#pragma unroll
        for (int g = 0; g < 4; ++g) {
            short8 b = *(const short8*)&Bs[(g * 16 + (lane & 15)) * 40 + (lane >> 4) * 8];
            acc[g] = __builtin_amdgcn_mfma_f32_16x16x32_bf16(a, b, acc[g], 0, 0, 0);
        }
        __syncthreads();
    }
#pragma unroll
    for (int g = 0; g < 4; ++g) {
        int col = n0 + g * 16 + (lane & 15);
        float bs = bias[col];
#pragma unroll
        for (int r = 0; r < 4; ++r) {
            int grow = m0 + wave * 16 + (lane >> 4) * 4 + r;
            if (grow < M) C[(size_t)grow * N + col] = f2bf(acc[g][r] + bs);
        }
    }
}

// ---------------------------------------------------------------------------
// helpers for gat_agg
// ---------------------------------------------------------------------------
template <int NV>
__device__ __forceinline__ void ld_row(float* r, const float* p) {
    if constexpr (NV == 4) {
        float4 t = *(const float4*)p;
        r[0] = t.x; r[1] = t.y; r[2] = t.z; r[3] = t.w;
    } else {
        float2 t = *(const float2*)p;
        r[0] = t.x; r[1] = t.y;
    }
}
template <int NV>
__device__ __forceinline__ uint2 ld_bf(const unsigned short* __restrict__ base, int laneoff) {
    uint2 r;
    if constexpr (NV == 4) r = *(const uint2*)(base + laneoff);
    else { r.x = *(const unsigned int*)(base + laneoff); r.y = 0; }
    return r;
}
template <int G>
__device__ __forceinline__ float grp_reduce(float vs) {
    vs = dpp_add<0xB1>(vs);              // xor 1
    vs = dpp_add<0x4E>(vs);              // xor 2
    vs = dpp_add<0x141>(vs);             // xor 4 (row_half_mirror)
    if constexpr (G >= 16) vs = dpp_add<0x140>(vs);   // xor 8 (row_mirror)
    if constexpr (G >= 32) {             // xor 16
        int t = __builtin_amdgcn_ds_swizzle(__float_as_int(vs), 0x401F);
        vs += __int_as_float(t);
    }
    if constexpr (G >= 64) vs += __shfl_xor(vs, 32, 64);
    return vs;
}

// ---------------------------------------------------------------------------
// Kernel 5: fused GATv2 gather(bf16) + score + softmax + aggregate + relu.
// One wave per dst node.  xl/xr live interleaved in one buffer (GEMM output):
// xl row = xlr + node*STRIDE, xr row = +HC.  Edges batch-loaded 64/vec-load,
// extracted via v_readlane (SGPR-base gathers), unroll-4 with 4 gather slots
// in flight.  Score: leakyrelu(m)*att == att6*m + att4*|m| (slope 0.2),
// |m| is a free VOP3 modifier.  DPP score reduction.
// ---------------------------------------------------------------------------
template <int HC, int STRIDE, int C, bool OUT_BF16>
__global__ void __launch_bounds__(256)
gat_agg(const unsigned short* __restrict__ xlr,
        const float* __restrict__ We, const float* __restrict__ att,
        const float* __restrict__ bias,
        const int* __restrict__ row_ptr, const int* __restrict__ ssrc,
        const float* __restrict__ sea, const float* __restrict__ ea_loop,
        void* __restrict__ out, int n) {
    constexpr int NV = HC / 64;
    constexpr int G  = C / NV;
    int wave = threadIdx.x >> 6;
    int lane = threadIdx.x & 63;
    int node = blockIdx.x * 4 + wave;
    if (node >= n) return;
    int laneoff = lane * NV;

    float xr_r[NV], We_r[NV], att6[NV], att4[NV], o[NV];
    {
        uint2 u = ld_bf<NV>(xlr + (size_t)node * STRIDE + HC, laneoff);
        if constexpr (NV == 4) { bf2f(u.x, xr_r[0], xr_r[1]); bf2f(u.y, xr_r[2], xr_r[3]); }
        else                   { bf2f(u.x, xr_r[0], xr_r[1]); }
    }
    ld_row<NV>(We_r, We + laneoff);
    {
        float att_r[NV];
        ld_row<NV>(att_r, att + laneoff);
#pragma unroll
        for (int j = 0; j < NV; ++j) { att6[j] = 0.6f * att_r[j]; att4[j] = 0.4f * att_r[j]; }
    }

    int start = __builtin_amdgcn_readfirstlane(row_ptr[node]);
    int end   = __builtin_amdgcn_readfirstlane(row_ptr[node + 1]);
    float ea_l = ea_loop[node];
    float l = 0.0f;
#pragma unroll
    for (int j = 0; j < NV; ++j) o[j] = 0.0f;

    // per-edge work: unpack, score via att6*m + att4*|m|, reduce, exp, accum
    auto process = [&](uint2 xu, float w) {
        float xf[NV];
        if constexpr (NV == 4) { bf2f(xu.x, xf[0], xf[1]); bf2f(xu.y, xf[2], xf[3]); }
        else                   { bf2f(xu.x, xf[0], xf[1]); }
        float vs = 0.0f;
#pragma unroll
        for (int j = 0; j < NV; ++j) {
            float mm = xf[j] + fmaf(w, We_r[j], xr_r[j]);
            vs = fmaf(att6[j], mm, vs);
            vs = fmaf(att4[j], fabsf(mm), vs);
        }
        vs = grp_reduce<G>(vs);
        float pr = __expf(vs);
        l += pr;
#pragma unroll
        for (int j = 0; j < NV; ++j) o[j] = fmaf(pr, xf[j], o[j]);
    };

    // ---- self-loop edge ----
    process(ld_bf<NV>(xlr + (size_t)node * STRIDE, laneoff), ea_l);

    // ---- real edges, batches of 64, unroll-4 with 4 slots in flight ----
    int cnt = end - start;
    for (int b0 = 0; b0 < cnt; b0 += 64) {
        int rem = imin(64, cnt - b0);
        int idx = start + b0 + lane;
        int idxc = imin(idx, end - 1);
        int   srcv = ssrc[idxc];
        float wvv  = sea[idxc];

        auto rl = [&](int j) {
            int s = __builtin_amdgcn_readlane(srcv, j);
            return ld_bf<NV>(xlr + (size_t)s * STRIDE, laneoff);
        };
        auto rw = [&](int j) {
            return __int_as_float(__builtin_amdgcn_readlane(__float_as_int(wvv), j));
        };

        int rc = rem - 1;
        uint2 X0 = rl(0),            X1 = rl(imin(1, rc)),
              X2 = rl(imin(2, rc)),  X3 = rl(imin(3, rc));
        float W0 = rw(0),            W1 = rw(imin(1, rc)),
              W2 = rw(imin(2, rc)),  W3 = rw(imin(3, rc));

        int j = 0;
        for (; j + 4 <= rem; j += 4) {
            uint2 Y0 = rl(imin(j + 4, rc)), Y1 = rl(imin(j + 5, rc)),
                  Y2 = rl(imin(j + 6, rc)), Y3 = rl(imin(j + 7, rc));
            float U0 = rw(imin(j + 4, rc)), U1 = rw(imin(j + 5, rc)),
                  U2 = rw(imin(j + 6, rc)), U3 = rw(imin(j + 7, rc));
            process(X0, W0); process(X1, W1); process(X2, W2); process(X3, W3);
            X0 = Y0; X1 = Y1; X2 = Y2; X3 = Y3;
            W0 = U0; W1 = U1; W2 = U2; W3 = U3;
        }
        if (j < rem) {
            process(X0, W0);
            if (j + 1 < rem) {
                process(X1, W1);
                if (j + 2 < rem) process(X2, W2);
            }
        }
    }

    float inv = 1.0f / (l + 1e-16f);
    float b_r[NV];
    ld_row<NV>(b_r, bias + laneoff);
    float v[NV];
#pragma unroll
    for (int j = 0; j < NV; ++j) v[j] = fmaxf(o[j] * inv + b_r[j], 0.0f);

    if constexpr (OUT_BF16) {
        unsigned short* op = (unsigned short*)out + (size_t)node * HC + laneoff;
        if constexpr (NV == 4) {
            uint2 t;
            t.x = (unsigned int)f2bf(v[0]) | ((unsigned int)f2bf(v[1]) << 16);
            t.y = (unsigned int)f2bf(v[2]) | ((unsigned int)f2bf(v[3]) << 16);
            *(uint2*)op = t;
        } else {
            *(unsigned int*)op = (unsigned int)f2bf(v[0]) | ((unsigned int)f2bf(v[1]) << 16);
        }
    } else {
        float* op = (float*)out + (size_t)node * HC + laneoff;
        if constexpr (NV == 4) { *(float4*)op = make_float4(v[0], v[1], v[2], v[3]); }
        else                   { *(float2*)op = make_float2(v[0], v[1]); }
    }
}

// ---------------------------------------------------------------------------
// Kernel 6: column partial sums of h2 [n,128] -> partial[gridDim.x*128]
// ---------------------------------------------------------------------------
__global__ void pool_partial(const float* __restrict__ h2, float* __restrict__ partial, int n) {
    int t = threadIdx.x;
    float s = 0.0f;
    for (int r = blockIdx.x; r < n; r += gridDim.x) s += h2[(size_t)r * 128 + t];
    partial[blockIdx.x * 128 + t] = s;
}

// ---------------------------------------------------------------------------
// Kernel 7: finish pooling, softmax over 128, sigmoid(alpha). 1024 threads.
// ---------------------------------------------------------------------------
__global__ void __launch_bounds__(1024)
pool_final(const float* __restrict__ partial, int nb,
           const float* __restrict__ alpha_in,
           float* __restrict__ out, int n) {
    __shared__ float acc[8][128];
    __shared__ float red[4];
    int t = threadIdx.x & 127;        // column
    int g = threadIdx.x >> 7;         // group 0..7
    float s = 0.0f;
    for (int b = g; b < nb; b += 8) s += partial[b * 128 + t];
    acc[g][t] = s;
    __syncthreads();
    if (threadIdx.x < 128) {
        float tot = 0.0f;
#pragma unroll
        for (int k = 0; k < 8; ++k) tot += acc[k][t];
        float mean = tot / (float)n;
        float mx = mean;
#pragma unroll
        for (int off = 32; off > 0; off >>= 1) mx = fmaxf(mx, __shfl_xor(mx, off, 64));
        if ((t & 63) == 0) red[t >> 6] = mx;
        __syncthreads();
        mx = fmaxf(red[0], red[1]);
        float ex = __expf(mean - mx);
        float sm = ex;
#pragma unroll
        for (int off = 32; off > 0; off >>= 1) sm += __shfl_xor(sm, off, 64);
        if ((t & 63) == 0) red[2 + (t >> 6)] = sm;
        __syncthreads();
        sm = red[2] + red[3];
        out[t] = ex / sm;
        if (t == 0) out[128] = 1.0f / (1.0f + __expf(-alpha_in[0]));
    }
}

// ---------------------------------------------------------------------------
extern "C" void kernel_launch(void* const* d_in, const int* in_sizes, int n_in,
                              void* d_out, int out_size, void* d_ws, size_t ws_size,
                              hipStream_t stream) {
    const float* x    = (const float*)d_in[0];
    const int*   ei   = (const int*)d_in[1];
    const float* ea   = (const float*)d_in[2];
    const float* W1l  = (const float*)d_in[3];
    const float* b1l  = (const float*)d_in[4];
    const float* W1r  = (const float*)d_in[5];
    const float* b1r  = (const float*)d_in[6];
    const float* We1  = (const float*)d_in[7];
    const float* att1 = (const float*)d_in[8];
    const float* bias1= (const float*)d_in[9];
    const float* W2l  = (const float*)d_in[10];
    const float* b2l  = (const float*)d_in[11];
    const float* W2r  = (const float*)d_in[12];
    const float* b2r  = (const float*)d_in[13];
    const float* We2  = (const float*)d_in[14];
    const float* att2 = (const float*)d_in[15];
    const float* bias2= (const float*)d_in[16];
    const float* alpha= (const float*)d_in[17];
    float* out = (float*)d_out;

    const int F = 128, HC1 = 256, HC2 = 128;
    const int n = in_sizes[0] / F;       // 20000
    const int E = in_sizes[1] / 2;       // 640000
    const int B = (n + 1023) / 1024;     // scan blocks

    char* ws = (char*)d_ws;
    size_t off = 0;
    auto alloc = [&](size_t bytes) { size_t p = off; off += (bytes + 255) & ~(size_t)255; return p; };

    int*   deg     = (int*)  (ws + alloc((size_t)n * 4));
    float* ea_sum  = (float*)(ws + alloc((size_t)n * 4));
    int*   row_ptr = (int*)  (ws + alloc((size_t)(n + 1) * 4));
    int*   wptr    = (int*)  (ws + alloc((size_t)n * 4));
    float* ea_loop = (float*)(ws + alloc((size_t)n * 4));
    int*   bsum    = (int*)  (ws + alloc(64 * 4));
    int*   ssrc    = (int*)  (ws + alloc((size_t)E * 4));
    float* sea     = (float*)(ws + alloc((size_t)E * 4));
    unsigned short* xb   = (unsigned short*)(ws + alloc((size_t)n * F * 2));
    unsigned short* Wt1  = (unsigned short*)(ws + alloc((size_t)F * (2 * HC1) * 2));
    unsigned short* Wt2  = (unsigned short*)(ws + alloc((size_t)HC1 * (2 * HC2) * 2));
    float* b1cat   = (float*)(ws + alloc((size_t)2 * HC1 * 4));
    float* b2cat   = (float*)(ws + alloc((size_t)2 * HC2 * 4));
    unsigned short* xlr1 = (unsigned short*)(ws + alloc((size_t)n * 2 * HC1 * 2));
    unsigned short* h1   = (unsigned short*)(ws + alloc((size_t)n * HC1 * 2));
    float* h2      = (float*)(ws + alloc((size_t)n * HC2 * 4));
    float* partial = (float*)(ws + alloc((size_t)256 * 128 * 4));
    unsigned short* xlr2 = xlr1;   // layer-2 projections alias layer-1 buffer
    const int NB_POOL = 256;

    (void)hipMemsetAsync(deg, 0, (size_t)n * 4, stream);
    (void)hipMemsetAsync(ea_sum, 0, (size_t)n * 4, stream);

    int tb = 256;
    edge_hist<<<(E + tb - 1) / tb, tb, 0, stream>>>(ei, ea, deg, ea_sum, E);
    scan_a<<<B, 256, 0, stream>>>(deg, bsum, n);
    scan_b<<<1, 64, 0, stream>>>(bsum, row_ptr, B, n);
    scan_c<<<B, 256, 0, stream>>>(deg, ea_sum, bsum, row_ptr, wptr, ea_loop, n);
    edge_scatter<<<(E + tb - 1) / tb, tb, 0, stream>>>(ei, ea, wptr, ssrc, sea, E);

    // conversions: x -> bf16; weights -> bf16 transposed, l/r concatenated
    cvt_bf16<<<(n * F + tb - 1) / tb, tb, 0, stream>>>(x, xb, n * F);
    tr_cvt_bf16<<<(F * HC1 + tb - 1) / tb, tb, 0, stream>>>(W1l, Wt1, F, HC1);
    tr_cvt_bf16<<<(F * HC1 + tb - 1) / tb, tb, 0, stream>>>(W1r, Wt1 + (size_t)HC1 * F, F, HC1);
    tr_cvt_bf16<<<(HC1 * HC2 + tb - 1) / tb, tb, 0, stream>>>(W2l, Wt2, HC1, HC2);
    tr_cvt_bf16<<<(HC1 * HC2 + tb - 1) / tb, tb, 0, stream>>>(W2r, Wt2 + (size_t)HC2 * HC1, HC1, HC2);
    bias_cat<<<(2 * HC1 + tb - 1) / tb, tb, 0, stream>>>(b1l, b1r, b1cat, HC1, 2 * HC1);
    bias_cat<<<(2 * HC2 + tb - 1) / tb, tb, 0, stream>>>(b2l, b2r, b2cat, HC2, 2 * HC2);

    // layer 1: one merged GEMM [n,128]@[128,512] -> xlr1 (xl | xr interleaved rows)
    {
        dim3 grid((n + 63) / 64, (2 * HC1) / 64);
        gemm_bf16<<<grid, 256, 0, stream>>>(xb, Wt1, b1cat, xlr1, n, 2 * HC1, F);
    }
    gat_agg<256, 512, 32, true><<<(n + 3) / 4, 256, 0, stream>>>(
        xlr1, We1, att1, bias1, row_ptr, ssrc, sea, ea_loop, h1, n);

    // layer 2: one merged GEMM [n,256]@[256,256] -> xlr2
    {
        dim3 grid((n + 63) / 64, (2 * HC2) / 64);
        gemm_bf16<<<grid, 256, 0, stream>>>(h1, Wt2, b2cat, xlr2, n, 2 * HC2, HC1);
    }
    gat_agg<128, 256, 128, false><<<(n + 3) / 4, 256, 0, stream>>>(
        xlr2, We2, att2, bias2, row_ptr, ssrc, sea, ea_loop, h2, n);

    pool_partial<<<NB_POOL, 128, 0, stream>>>(h2, partial, n);
    pool_final<<<1, 1024, 0, stream>>>(partial, NB_POOL, alpha, out, n);
}

// Round 8
// 319.271 us; speedup vs baseline: 2.1513x; 1.1193x over previous
//
#include <hip/hip_runtime.h>
#include <math.h>

#define NEG_SLOPE 0.2f

typedef __attribute__((ext_vector_type(8))) short short8;   // 8 bf16 (4 VGPRs)
typedef __attribute__((ext_vector_type(4))) float f32x4;

__device__ __forceinline__ int imin(int a, int b) { return a < b ? a : b; }

__device__ __forceinline__ unsigned int f2bf(float f) {
    unsigned int u = __float_as_uint(f);
    return (u + 0x7fffu + ((u >> 16) & 1u)) >> 16;   // RNE
}
__device__ __forceinline__ void bf2f(unsigned int u, float& a, float& b) {
    a = __uint_as_float(u << 16);
    b = __uint_as_float(u & 0xffff0000u);
}
template <int CTRL>
__device__ __forceinline__ float dpp_add(float v) {
    int t = __builtin_amdgcn_update_dpp(0, __float_as_int(v), CTRL, 0xF, 0xF, true);
    return v + __int_as_float(t);
}

// ---------------------------------------------------------------------------
// Kernel 1: packed histogram. One 64-bit atomic per edge onto a 64B-padded
// slot: low 32 = count, high 32 = ea sum in 2^-16 fixed point.
// (count never carries into high; |sum_fix| << 2^31.)
// ---------------------------------------------------------------------------
__global__ void edge_hist(const int* __restrict__ ei, const float* __restrict__ ea,
                          unsigned long long* __restrict__ hist, int E) {
    int e = blockIdx.x * blockDim.x + threadIdx.x;
    if (e < E) {
        int d = ei[E + e];
        long long fx = (long long)__float2int_rn(ea[e] * 65536.0f);
        unsigned long long v = ((unsigned long long)fx << 32) | 1ull;
        atomicAdd(&hist[(size_t)d * 8], v);
    }
}

// ---------------------------------------------------------------------------
// 3-phase parallel scan over hist (padded stride 8).
// ---------------------------------------------------------------------------
__global__ void scan_a(const unsigned long long* __restrict__ hist, int* __restrict__ bsum, int n) {
    __shared__ int wred[4];
    int base = blockIdx.x * 1024;
    int tid = threadIdx.x;
    int s = 0;
#pragma unroll
    for (int k = 0; k < 4; ++k) {
        int i = base + tid + k * 256;
        if (i < n) s += (int)(hist[(size_t)i * 8] & 0xffffffffull);
    }
#pragma unroll
    for (int off = 32; off > 0; off >>= 1) s += __shfl_xor(s, off, 64);
    if ((tid & 63) == 0) wred[tid >> 6] = s;
    __syncthreads();
    if (tid == 0) bsum[blockIdx.x] = wred[0] + wred[1] + wred[2] + wred[3];
}

__global__ void scan_b(int* __restrict__ bsum, int* __restrict__ row_ptr, int B, int n) {
    int tid = threadIdx.x;           // 64 threads, B <= 64
    int v = (tid < B) ? bsum[tid] : 0;
    int s = v;
#pragma unroll
    for (int off = 1; off < 64; off <<= 1) {
        int t = __shfl_up(s, off, 64);
        if (tid >= off) s += t;
    }
    if (tid < B) bsum[tid] = s - v;  // exclusive
    if (tid == 63) row_ptr[n] = s;   // total
}

__global__ void scan_c(const unsigned long long* __restrict__ hist,
                       const int* __restrict__ bsum, int* __restrict__ row_ptr,
                       int* __restrict__ wptr_pad, float* __restrict__ ea_loop, int n) {
    __shared__ int wtot[4];
    int tid = threadIdx.x;
    int wid = tid >> 6, lane = tid & 63;
    int i0 = blockIdx.x * 1024 + tid * 4;
    int dcnt[4]; float esum[4];
#pragma unroll
    for (int k = 0; k < 4; ++k) {
        if (i0 + k < n) {
            unsigned long long h = hist[(size_t)(i0 + k) * 8];
            dcnt[k] = (int)(h & 0xffffffffull);
            esum[k] = (float)((int)(h >> 32)) * (1.0f / 65536.0f);
        } else { dcnt[k] = 0; esum[k] = 0.0f; }
    }
    int tsum = dcnt[0] + dcnt[1] + dcnt[2] + dcnt[3];
    int s = tsum;
#pragma unroll
    for (int off = 1; off < 64; off <<= 1) {
        int t = __shfl_up(s, off, 64);
        if (lane >= off) s += t;
    }
    if (lane == 63) wtot[wid] = s;
    __syncthreads();
    int wpre = 0;
#pragma unroll
    for (int k = 0; k < 4; ++k) if (k < wid) wpre += wtot[k];
    int pre = bsum[blockIdx.x] + wpre + (s - tsum);
    if (i0 < n) {
        int4 e;
        e.x = pre;
        e.y = pre + dcnt[0];
        e.z = e.y + dcnt[1];
        e.w = e.z + dcnt[2];
        *(int4*)(row_ptr + i0) = e;
        int ev[4] = { e.x, e.y, e.z, e.w };
        float4 el;
        el.x = esum[0] / fmaxf((float)dcnt[0], 1.0f);
        el.y = esum[1] / fmaxf((float)dcnt[1], 1.0f);
        el.z = esum[2] / fmaxf((float)dcnt[2], 1.0f);
        el.w = esum[3] / fmaxf((float)dcnt[3], 1.0f);
        *(float4*)(ea_loop + i0) = el;
#pragma unroll
        for (int k = 0; k < 4; ++k) wptr_pad[(size_t)(i0 + k) * 16] = ev[k];
    }
}

// ---------------------------------------------------------------------------
// Kernel 3: scatter edges into CSR order; (src,w) packed as int2.
// wptr padded 1/cacheline to avoid false-sharing serialization.
// ---------------------------------------------------------------------------
__global__ void edge_scatter(const int* __restrict__ ei, const float* __restrict__ ea,
                             int* __restrict__ wptr_pad, int2* __restrict__ spk, int E) {
    int e = blockIdx.x * blockDim.x + threadIdx.x;
    if (e < E) {
        int d = ei[E + e];
        int pos = atomicAdd(&wptr_pad[(size_t)d * 16], 1);
        spk[pos] = make_int2(ei[e], __float_as_int(ea[e]));
    }
}

// ---------------------------------------------------------------------------
// Conversion kernels
// ---------------------------------------------------------------------------
__global__ void cvt_bf16_v4(const float* __restrict__ in, unsigned short* __restrict__ out, int sz4) {
    int i = blockIdx.x * blockDim.x + threadIdx.x;
    if (i < sz4) {
        float4 v = ((const float4*)in)[i];
        uint2 r;
        r.x = f2bf(v.x) | (f2bf(v.y) << 16);
        r.y = f2bf(v.z) | (f2bf(v.w) << 16);
        ((uint2*)out)[i] = r;
    }
}
__global__ void tr_cvt_bf16(const float* __restrict__ in, unsigned short* __restrict__ out,
                            int K, int N) {
    int i = blockIdx.x * blockDim.x + threadIdx.x;
    if (i < K * N) {
        int k = i / N, nn = i - k * N;
        out[nn * K + k] = (unsigned short)f2bf(in[i]);
    }
}
__global__ void bias_cat(const float* __restrict__ a, const float* __restrict__ b,
                         float* __restrict__ out, int na, int ntot) {
    int i = blockIdx.x * blockDim.x + threadIdx.x;
    if (i < ntot) out[i] = (i < na) ? a[i] : b[i - na];
}

// ---------------------------------------------------------------------------
// Kernel 4: bf16 MFMA GEMM + bias (B pre-transposed), 64x64 tile, BK=32.
// ---------------------------------------------------------------------------
__global__ void __launch_bounds__(256)
gemm_bf16(const unsigned short* __restrict__ A, const unsigned short* __restrict__ Bt,
          const float* __restrict__ bias, unsigned short* __restrict__ C,
          int M, int N, int K) {
    __shared__ __attribute__((aligned(16))) unsigned short As[64 * 40];
    __shared__ __attribute__((aligned(16))) unsigned short Bs[64 * 40];
    int tid  = threadIdx.x;
    int wave = tid >> 6, lane = tid & 63;
    int m0 = blockIdx.x * 64, n0 = blockIdx.y * 64;
    int row = tid >> 2, kg = (tid & 3) * 8;

    f32x4 acc[4] = {};
    for (int kk = 0; kk < K; kk += 32) {
        int gm = m0 + row;
        uint4 av;
        if (gm < M) av = *(const uint4*)(A + (size_t)gm * K + kk + kg);
        else        av = make_uint4(0, 0, 0, 0);
        *(uint4*)&As[row * 40 + kg] = av;
        uint4 bv = *(const uint4*)(Bt + (size_t)(n0 + row) * K + kk + kg);
        *(uint4*)&Bs[row * 40 + kg] = bv;
        __syncthreads();
        short8 a = *(const short8*)&As[(wave * 16 + (lane & 15)) * 40 + (lane >> 4) * 8];
#pragma unroll
        for (int g = 0; g < 4; ++g) {
            short8 b = *(const short8*)&Bs[(g * 16 + (lane & 15)) * 40 + (lane >> 4) * 8];
            acc[g] = __builtin_amdgcn_mfma_f32_16x16x32_bf16(a, b, acc[g], 0, 0, 0);
        }
        __syncthreads();
    }
#pragma unroll
    for (int g = 0; g < 4; ++g) {
        int col = n0 + g * 16 + (lane & 15);
        float bs = bias[col];
#pragma unroll
        for (int r = 0; r < 4; ++r) {
            int grow = m0 + wave * 16 + (lane >> 4) * 4 + r;
            if (grow < M) C[(size_t)grow * N + col] = (unsigned short)f2bf(acc[g][r] + bs);
        }
    }
}

// ---------------------------------------------------------------------------
// helpers for gat_agg
// ---------------------------------------------------------------------------
template <int NV>
__device__ __forceinline__ void ld_row(float* r, const float* p) {
    if constexpr (NV == 4) {
        float4 t = *(const float4*)p;
        r[0] = t.x; r[1] = t.y; r[2] = t.z; r[3] = t.w;
    } else {
        float2 t = *(const float2*)p;
        r[0] = t.x; r[1] = t.y;
    }
}
template <int NV>
__device__ __forceinline__ uint2 ld_bf(const unsigned short* __restrict__ base, int laneoff) {
    uint2 r;
    if constexpr (NV == 4) r = *(const uint2*)(base + laneoff);
    else { r.x = *(const unsigned int*)(base + laneoff); r.y = 0; }
    return r;
}
template <int G>
__device__ __forceinline__ float grp_reduce(float vs) {
    vs = dpp_add<0xB1>(vs);              // xor 1
    vs = dpp_add<0x4E>(vs);              // xor 2
    vs = dpp_add<0x141>(vs);             // xor 4 (row_half_mirror)
    if constexpr (G >= 16) vs = dpp_add<0x140>(vs);   // xor 8 (row_mirror)
    if constexpr (G >= 32) {             // xor 16
        int t = __builtin_amdgcn_ds_swizzle(__float_as_int(vs), 0x401F);
        vs += __int_as_float(t);
    }
    if constexpr (G >= 64) vs += __shfl_xor(vs, 32, 64);
    return vs;
}

// ---------------------------------------------------------------------------
// Kernel 5: fused GATv2 gather(bf16) + score + softmax + aggregate + relu.
// One wave per dst node; xl/xr interleaved rows in xlr (stride STRIDE).
// Edge (src,w) int2 batch-loaded 64/vec-load, extracted via v_readlane
// (SGPR-base gathers), unroll-4 with 4 gather slots in flight.
// Score: leakyrelu(m)*att == att6*m + att4*|m| (slope 0.2).
// ---------------------------------------------------------------------------
template <int HC, int STRIDE, int C, bool OUT_BF16>
__global__ void __launch_bounds__(256)
gat_agg(const unsigned short* __restrict__ xlr,
        const float* __restrict__ We, const float* __restrict__ att,
        const float* __restrict__ bias,
        const int* __restrict__ row_ptr, const int2* __restrict__ spk,
        const float* __restrict__ ea_loop,
        void* __restrict__ out, int n) {
    constexpr int NV = HC / 64;
    constexpr int G  = C / NV;
    int wave = threadIdx.x >> 6;
    int lane = threadIdx.x & 63;
    int node = blockIdx.x * 4 + wave;
    if (node >= n) return;
    int laneoff = lane * NV;

    float xr_r[NV], We_r[NV], att6[NV], att4[NV], o[NV];
    {
        uint2 u = ld_bf<NV>(xlr + (size_t)node * STRIDE + HC, laneoff);
        if constexpr (NV == 4) { bf2f(u.x, xr_r[0], xr_r[1]); bf2f(u.y, xr_r[2], xr_r[3]); }
        else                   { bf2f(u.x, xr_r[0], xr_r[1]); }
    }
    ld_row<NV>(We_r, We + laneoff);
    {
        float att_r[NV];
        ld_row<NV>(att_r, att + laneoff);
#pragma unroll
        for (int j = 0; j < NV; ++j) { att6[j] = 0.6f * att_r[j]; att4[j] = 0.4f * att_r[j]; }
    }

    int start = __builtin_amdgcn_readfirstlane(row_ptr[node]);
    int end   = __builtin_amdgcn_readfirstlane(row_ptr[node + 1]);
    float ea_l = ea_loop[node];
    float l = 0.0f;
#pragma unroll
    for (int j = 0; j < NV; ++j) o[j] = 0.0f;

    auto process = [&](uint2 xu, float w) {
        float xf[NV];
        if constexpr (NV == 4) { bf2f(xu.x, xf[0], xf[1]); bf2f(xu.y, xf[2], xf[3]); }
        else                   { bf2f(xu.x, xf[0], xf[1]); }
        float vs = 0.0f;
#pragma unroll
        for (int j = 0; j < NV; ++j) {
            float mm = xf[j] + fmaf(w, We_r[j], xr_r[j]);
            vs = fmaf(att6[j], mm, vs);
            vs = fmaf(att4[j], fabsf(mm), vs);
        }
        vs = grp_reduce<G>(vs);
        float pr = __expf(vs);
        l += pr;
#pragma unroll
        for (int j = 0; j < NV; ++j) o[j] = fmaf(pr, xf[j], o[j]);
    };

    // ---- self-loop edge ----
    process(ld_bf<NV>(xlr + (size_t)node * STRIDE, laneoff), ea_l);

    // ---- real edges, batches of 64, unroll-4 with 4 slots in flight ----
    int cnt = end - start;
    for (int b0 = 0; b0 < cnt; b0 += 64) {
        int rem = imin(64, cnt - b0);
        int idx = start + b0 + lane;
        int idxc = imin(idx, end - 1);
        int2 pv = spk[idxc];

        auto rl = [&](int j) {
            int s = __builtin_amdgcn_readlane(pv.x, j);
            return ld_bf<NV>(xlr + (size_t)s * STRIDE, laneoff);
        };
        auto rw = [&](int j) {
            return __int_as_float(__builtin_amdgcn_readlane(pv.y, j));
        };

        int rc = rem - 1;
        uint2 X0 = rl(0),            X1 = rl(imin(1, rc)),
              X2 = rl(imin(2, rc)),  X3 = rl(imin(3, rc));
        float W0 = rw(0),            W1 = rw(imin(1, rc)),
              W2 = rw(imin(2, rc)),  W3 = rw(imin(3, rc));

        int j = 0;
        for (; j + 4 <= rem; j += 4) {
            uint2 Y0 = rl(imin(j + 4, rc)), Y1 = rl(imin(j + 5, rc)),
                  Y2 = rl(imin(j + 6, rc)), Y3 = rl(imin(j + 7, rc));
            float U0 = rw(imin(j + 4, rc)), U1 = rw(imin(j + 5, rc)),
                  U2 = rw(imin(j + 6, rc)), U3 = rw(imin(j + 7, rc));
            process(X0, W0); process(X1, W1); process(X2, W2); process(X3, W3);
            X0 = Y0; X1 = Y1; X2 = Y2; X3 = Y3;
            W0 = U0; W1 = U1; W2 = U2; W3 = U3;
        }
        if (j < rem) {
            process(X0, W0);
            if (j + 1 < rem) {
                process(X1, W1);
                if (j + 2 < rem) process(X2, W2);
            }
        }
    }

    float inv = 1.0f / (l + 1e-16f);
    float b_r[NV];
    ld_row<NV>(b_r, bias + laneoff);
    float v[NV];
#pragma unroll
    for (int j = 0; j < NV; ++j) v[j] = fmaxf(o[j] * inv + b_r[j], 0.0f);

    if constexpr (OUT_BF16) {
        unsigned short* op = (unsigned short*)out + (size_t)node * HC + laneoff;
        if constexpr (NV == 4) {
            uint2 t;
            t.x = f2bf(v[0]) | (f2bf(v[1]) << 16);
            t.y = f2bf(v[2]) | (f2bf(v[3]) << 16);
            *(uint2*)op = t;
        } else {
            *(unsigned int*)op = f2bf(v[0]) | (f2bf(v[1]) << 16);
        }
    } else {
        float* op = (float*)out + (size_t)node * HC + laneoff;
        if constexpr (NV == 4) { *(float4*)op = make_float4(v[0], v[1], v[2], v[3]); }
        else                   { *(float2*)op = make_float2(v[0], v[1]); }
    }
}

// ---------------------------------------------------------------------------
// Kernel 6: column partial sums of h2 [n,128] -> partial[gridDim.x*128]
// ---------------------------------------------------------------------------
__global__ void pool_partial(const float* __restrict__ h2, float* __restrict__ partial, int n) {
    int t = threadIdx.x;
    float s = 0.0f;
    for (int r = blockIdx.x; r < n; r += gridDim.x) s += h2[(size_t)r * 128 + t];
    partial[blockIdx.x * 128 + t] = s;
}

// ---------------------------------------------------------------------------
// Kernel 7: finish pooling, softmax over 128, sigmoid(alpha). 1024 threads.
// ---------------------------------------------------------------------------
__global__ void __launch_bounds__(1024)
pool_final(const float* __restrict__ partial, int nb,
           const float* __restrict__ alpha_in,
           float* __restrict__ out, int n) {
    __shared__ float acc[8][128];
    __shared__ float red[4];
    int t = threadIdx.x & 127;        // column
    int g = threadIdx.x >> 7;         // group 0..7
    float s = 0.0f;
    for (int b = g; b < nb; b += 8) s += partial[b * 128 + t];
    acc[g][t] = s;
    __syncthreads();
    if (threadIdx.x < 128) {
        float tot = 0.0f;
#pragma unroll
        for (int k = 0; k < 8; ++k) tot += acc[k][t];
        float mean = tot / (float)n;
        float mx = mean;
#pragma unroll
        for (int off = 32; off > 0; off >>= 1) mx = fmaxf(mx, __shfl_xor(mx, off, 64));
        if ((t & 63) == 0) red[t >> 6] = mx;
        __syncthreads();
        mx = fmaxf(red[0], red[1]);
        float ex = __expf(mean - mx);
        float sm = ex;
#pragma unroll
        for (int off = 32; off > 0; off >>= 1) sm += __shfl_xor(sm, off, 64);
        if ((t & 63) == 0) red[2 + (t >> 6)] = sm;
        __syncthreads();
        sm = red[2] + red[3];
        out[t] = ex / sm;
        if (t == 0) out[128] = 1.0f / (1.0f + __expf(-alpha_in[0]));
    }
}

// ---------------------------------------------------------------------------
extern "C" void kernel_launch(void* const* d_in, const int* in_sizes, int n_in,
                              void* d_out, int out_size, void* d_ws, size_t ws_size,
                              hipStream_t stream) {
    const float* x    = (const float*)d_in[0];
    const int*   ei   = (const int*)d_in[1];
    const float* ea   = (const float*)d_in[2];
    const float* W1l  = (const float*)d_in[3];
    const float* b1l  = (const float*)d_in[4];
    const float* W1r  = (const float*)d_in[5];
    const float* b1r  = (const float*)d_in[6];
    const float* We1  = (const float*)d_in[7];
    const float* att1 = (const float*)d_in[8];
    const float* bias1= (const float*)d_in[9];
    const float* W2l  = (const float*)d_in[10];
    const float* b2l  = (const float*)d_in[11];
    const float* W2r  = (const float*)d_in[12];
    const float* b2r  = (const float*)d_in[13];
    const float* We2  = (const float*)d_in[14];
    const float* att2 = (const float*)d_in[15];
    const float* bias2= (const float*)d_in[16];
    const float* alpha= (const float*)d_in[17];
    float* out = (float*)d_out;

    const int F = 128, HC1 = 256, HC2 = 128;
    const int n = in_sizes[0] / F;       // 20000
    const int E = in_sizes[1] / 2;       // 640000
    const int B = (n + 1023) / 1024;     // scan blocks

    char* ws = (char*)d_ws;
    size_t off = 0;
    auto alloc = [&](size_t bytes) { size_t p = off; off += (bytes + 255) & ~(size_t)255; return p; };

    unsigned long long* hist = (unsigned long long*)(ws + alloc((size_t)n * 8 * 8));  // padded x8
    int*   row_ptr = (int*)  (ws + alloc((size_t)(n + 1) * 4));
    int*   wptr    = (int*)  (ws + alloc((size_t)n * 16 * 4));                        // padded x16
    float* ea_loop = (float*)(ws + alloc((size_t)n * 4));
    int*   bsum    = (int*)  (ws + alloc(64 * 4));
    int2*  spk     = (int2*) (ws + alloc((size_t)E * 8));
    unsigned short* xb   = (unsigned short*)(ws + alloc((size_t)n * F * 2));
    unsigned short* Wt1  = (unsigned short*)(ws + alloc((size_t)F * (2 * HC1) * 2));
    unsigned short* Wt2  = (unsigned short*)(ws + alloc((size_t)HC1 * (2 * HC2) * 2));
    float* b1cat   = (float*)(ws + alloc((size_t)2 * HC1 * 4));
    float* b2cat   = (float*)(ws + alloc((size_t)2 * HC2 * 4));
    unsigned short* xlr1 = (unsigned short*)(ws + alloc((size_t)n * 2 * HC1 * 2));
    unsigned short* h1   = (unsigned short*)(ws + alloc((size_t)n * HC1 * 2));
    float* h2      = (float*)(ws + alloc((size_t)n * HC2 * 4));
    float* partial = (float*)(ws + alloc((size_t)256 * 128 * 4));
    unsigned short* xlr2 = xlr1;   // layer-2 projections alias layer-1 buffer
    const int NB_POOL = 256;

    (void)hipMemsetAsync(hist, 0, (size_t)n * 8 * 8, stream);

    int tb = 256;
    edge_hist<<<(E + tb - 1) / tb, tb, 0, stream>>>(ei, ea, hist, E);
    scan_a<<<B, 256, 0, stream>>>(hist, bsum, n);
    scan_b<<<1, 64, 0, stream>>>(bsum, row_ptr, B, n);
    scan_c<<<B, 256, 0, stream>>>(hist, bsum, row_ptr, wptr, ea_loop, n);
    edge_scatter<<<(E + tb - 1) / tb, tb, 0, stream>>>(ei, ea, wptr, spk, E);

    // conversions: x -> bf16 (vec4); weights -> bf16 transposed, l/r concatenated
    cvt_bf16_v4<<<(n * F / 4 + tb - 1) / tb, tb, 0, stream>>>(x, xb, n * F / 4);
    tr_cvt_bf16<<<(F * HC1 + tb - 1) / tb, tb, 0, stream>>>(W1l, Wt1, F, HC1);
    tr_cvt_bf16<<<(F * HC1 + tb - 1) / tb, tb, 0, stream>>>(W1r, Wt1 + (size_t)HC1 * F, F, HC1);
    tr_cvt_bf16<<<(HC1 * HC2 + tb - 1) / tb, tb, 0, stream>>>(W2l, Wt2, HC1, HC2);
    tr_cvt_bf16<<<(HC1 * HC2 + tb - 1) / tb, tb, 0, stream>>>(W2r, Wt2 + (size_t)HC2 * HC1, HC1, HC2);
    bias_cat<<<(2 * HC1 + tb - 1) / tb, tb, 0, stream>>>(b1l, b1r, b1cat, HC1, 2 * HC1);
    bias_cat<<<(2 * HC2 + tb - 1) / tb, tb, 0, stream>>>(b2l, b2r, b2cat, HC2, 2 * HC2);

    // layer 1: one merged GEMM [n,128]@[128,512] -> xlr1 (xl | xr rows)
    {
        dim3 grid((n + 63) / 64, (2 * HC1) / 64);
        gemm_bf16<<<grid, 256, 0, stream>>>(xb, Wt1, b1cat, xlr1, n, 2 * HC1, F);
    }
    gat_agg<256, 512, 32, true><<<(n + 3) / 4, 256, 0, stream>>>(
        xlr1, We1, att1, bias1, row_ptr, spk, ea_loop, h1, n);

    // layer 2: one merged GEMM [n,256]@[256,256] -> xlr2
    {
        dim3 grid((n + 63) / 64, (2 * HC2) / 64);
        gemm_bf16<<<grid, 256, 0, stream>>>(h1, Wt2, b2cat, xlr2, n, 2 * HC2, HC1);
    }
    gat_agg<128, 256, 128, false><<<(n + 3) / 4, 256, 0, stream>>>(
        xlr2, We2, att2, bias2, row_ptr, spk, ea_loop, h2, n);

    pool_partial<<<NB_POOL, 128, 0, stream>>>(h2, partial, n);
    pool_final<<<1, 1024, 0, stream>>>(partial, NB_POOL, alpha, out, n);
}